// Round 9
// baseline (510.565 us; speedup 1.0000x reference)
//
#include <hip/hip_runtime.h>
#include <hip/hip_bf16.h>

// GATNodeEdgePrediction on MI355X (gfx950) — Round 9.
//  - att projections fused into GEMM epilogues: gemm128 EPI5 computes
//    att_s/att_d from the fp32 accumulators (each wave holds one full head
//    for 64 rows: 4 FMA + 16-lane shuffle tree per row); gemm64 EPI5 (W3)
//    ditto with an LDS combine across the two col-waves. att kernels deleted.
//  - agg4 back to 4-deep unroll (VGPR 24, occupancy ~70%) + inline qsum.
//  - 14 dispatches (was 17).

typedef unsigned short u16;
typedef unsigned int   u32;
typedef __attribute__((ext_vector_type(8))) short short8;
typedef __attribute__((ext_vector_type(4))) float float4v;

typedef const __attribute__((address_space(1))) u32* gptr_t;
typedef __attribute__((address_space(3))) u32* lptr_t;
#define GLOAD_LDS16(g, l) \
    __builtin_amdgcn_global_load_lds((gptr_t)(const void*)(g), (lptr_t)(void*)(l), 16, 0, 0)

static __device__ __forceinline__ u16 f2b(float f) {
    u32 u = __float_as_uint(f);
    u32 r = u + 0x7fffu + ((u >> 16) & 1u);  // RNE
    return (u16)(r >> 16);
}
static __device__ __forceinline__ float b2f(u16 u) {
    return __uint_as_float(((u32)u) << 16);
}
static __device__ __forceinline__ float lo2f(u32 v) { return __uint_as_float(v << 16); }
static __device__ __forceinline__ float hi2f(u32 v) { return __uint_as_float(v & 0xffff0000u); }
static __device__ __forceinline__ float lrelu02(float x) { return fmaxf(x, 0.2f * x); }

// ---------------------------------------------------------------- merged prep
__global__ void prep_mega(const float* __restrict__ x, u16* __restrict__ xb, int n4,
                          const float* s0, const float* s1, const float* s2,
                          const float* s3, const float* s4, const float* s5,
                          const float* s6, const float* s7,
                          u16* d0, u16* d1, u16* d2, u16* d3,
                          u16* d4, u16* d5, u16* d6, u16* d7,
                          const float* We1, const float* ae1,
                          const float* We2, const float* ae2,
                          const float* We3, const float* ae3, float* ce_g,
                          const int* __restrict__ ei,
                          u32* deg, u32* rank, int E) {
    int role = blockIdx.y;
    if (role == 0) {
        int i = blockIdx.x * 256 + threadIdx.x;
        if (i >= n4) return;
        float4 v = ((const float4*)x)[i];
        ushort4 o;
        o.x = f2b(v.x); o.y = f2b(v.y); o.z = f2b(v.z); o.w = f2b(v.w);
        ((ushort4*)xb)[i] = o;
    } else if (role == 2) {
        int e = blockIdx.x * 256 + threadIdx.x;
        if (e >= E) return;
        int d = ei[E + e];
        rank[e] = atomicAdd(&deg[d], 1u);
    } else {
        int wid = blockIdx.x >> 4, sub = blockIdx.x & 15;
        if (wid > 8) return;
        if (wid == 8) {
            if (sub == 0) {
                int t = threadIdx.x;
                if (t < 9) {
                    const float* W; const float* a; int h;
                    if (t < 4)      { W = We1; a = ae1; h = t; }
                    else if (t < 8) { W = We2; a = ae2; h = t - 4; }
                    else            { W = We3; a = ae3; h = 0; }
                    float s = 0.f;
                    for (int c = 0; c < 64; c++) s += W[h * 64 + c] * a[h * 64 + c];
                    ce_g[t] = s;
                }
            }
            return;
        }
        const float* src; u16* dst; int K, N;
        switch (wid) {
            case 0: src = s0; dst = d0; K = 128; N = 128; break;
            case 1: src = s1; dst = d1; K = 128; N = 256; break;
            case 2: src = s2; dst = d2; K = 128; N = 256; break;
            case 3: src = s3; dst = d3; K = 256; N = 256; break;
            case 4: src = s4; dst = d4; K = 256; N = 256; break;
            case 5: src = s5; dst = d5; K = 256; N = 64;  break;
            case 6: src = s6; dst = d6; K = 128; N = 64;  break;
            default: src = s7; dst = d7; K = 64;  N = 64;  break;
        }
        int KN = K * N;
        int nmask = N - 1;
        int nshift = __popc((u32)nmask);
        for (int i = sub * 256 + threadIdx.x; i < KN; i += 16 * 256) {
            int k = i >> nshift, n2 = i & nmask;
            dst[(size_t)n2 * K + k] = f2b(src[i]);
        }
    }
}

// ---------------------------------------------------------------- CSR build
__global__ void scan_block_kernel(const u32* __restrict__ deg, int* incl,
                                  int* blocksum, int Nn) {
    __shared__ int sb[256];
    int t = threadIdx.x;
    int n = blockIdx.x * 256 + t;
    int v = (n < Nn) ? (int)deg[n] : 0;
    sb[t] = v;
    __syncthreads();
    for (int off = 1; off < 256; off <<= 1) {
        int x = (t >= off) ? sb[t - off] : 0;
        __syncthreads();
        sb[t] += x;
        __syncthreads();
    }
    if (n < Nn) incl[n] = sb[t];
    if (t == 255) blocksum[blockIdx.x] = sb[255];
}

__global__ void scan_final_kernel(const u32* __restrict__ deg, const int* __restrict__ incl,
                                  const int* __restrict__ blocksum,
                                  int* row_ptr, int Nn) {
    __shared__ int sb[256];
    int t = threadIdx.x;
    int b = blockIdx.x;
    sb[t] = (t < b) ? blocksum[t] : 0;   // gridDim <= 256
    __syncthreads();
    for (int off = 128; off > 0; off >>= 1) {
        if (t < off) sb[t] += sb[t + off];
        __syncthreads();
    }
    int base = sb[0];
    int n = b * 256 + t;
    if (n >= Nn) return;
    int d = (int)deg[n];
    int excl = base + incl[n] - d;
    row_ptr[n] = excl;
    if (n == Nn - 1) row_ptr[Nn] = excl + d;
}

__global__ void scatter_kernel(const int* __restrict__ ei, const float* __restrict__ ea,
                               const int* __restrict__ row_ptr, const u32* __restrict__ rank,
                               int2* __restrict__ csr2, int E) {
    int e = blockIdx.x * 256 + threadIdx.x;
    if (e >= E) return;
    int d = ei[E + e];
    int pos = row_ptr[d] + (int)rank[e];
    csr2[pos] = make_int2(ei[e], __float_as_int(ea[e]));
}

// ---------------------------------------------------------------- GEMM 128x128
// EPI 5: col<256 -> fp32 Cf (+bias); col>=256 -> bf16 Cb AND fused att dots:
// each wave holds one full head (64 cols) x 64 rows in acc -> att_s/att_d.
template <int EPI, int K>
__global__ __launch_bounds__(256)
void gemm128_kernel(const u16* __restrict__ A, const u16* __restrict__ Bt,
                    const float* __restrict__ bias,
                    float* __restrict__ Cf, u16* __restrict__ Cb,
                    const float* __restrict__ a_s, const float* __restrict__ a_d,
                    float* __restrict__ att_s, float* __restrict__ att_d, int Nn) {
    __shared__ u16 As[128 * 32];
    __shared__ u16 Bs[128 * 32];
    int t = threadIdx.x;
    int w = t >> 6, lane = t & 63;
    int wm = w & 1, wn = w >> 1;
    int lm = lane & 15, q = lane >> 4;
    int bm = blockIdx.x * 128, bn = blockIdx.y * 128;

    float4v acc[4][4];
#pragma unroll
    for (int i = 0; i < 4; i++)
#pragma unroll
        for (int j = 0; j < 4; j++) acc[i][j] = (float4v){0.f, 0.f, 0.f, 0.f};

    int srow = lane >> 2;
    int scol = (lane & 3) * 8;
    const u16* aG = A + (size_t)(bm + w * 32 + srow) * K + scol;
    const u16* bG = Bt + (size_t)(bn + w * 32 + srow) * K + scol;
    u16* aL0 = &As[(w * 32) * 32];
    u16* aL1 = &As[(w * 32 + 16) * 32];
    u16* bL0 = &Bs[(w * 32) * 32];
    u16* bL1 = &Bs[(w * 32 + 16) * 32];

#pragma unroll
    for (int k0 = 0; k0 < K; k0 += 32) {
        GLOAD_LDS16(aG + k0, aL0);
        GLOAD_LDS16(aG + (size_t)16 * K + k0, aL1);
        GLOAD_LDS16(bG + k0, bL0);
        GLOAD_LDS16(bG + (size_t)16 * K + k0, bL1);
        __syncthreads();

        short8 af[4], bf[4];
#pragma unroll
        for (int i = 0; i < 4; i++)
            af[i] = *(const short8*)&As[(64 * wm + 16 * i + lm) * 32 + q * 8];
#pragma unroll
        for (int j = 0; j < 4; j++)
            bf[j] = *(const short8*)&Bs[(64 * wn + 16 * j + lm) * 32 + q * 8];
#pragma unroll
        for (int i = 0; i < 4; i++)
#pragma unroll
            for (int j = 0; j < 4; j++)
                acc[i][j] = __builtin_amdgcn_mfma_f32_16x16x32_bf16(af[i], bf[j], acc[i][j], 0, 0, 0);
        __syncthreads();
    }

    bool hside = (EPI == 5) && (blockIdx.y >= 2);
#pragma unroll
    for (int i = 0; i < 4; i++)
#pragma unroll
        for (int j = 0; j < 4; j++) {
            int col = bn + 64 * wn + 16 * j + lm;
#pragma unroll
            for (int r = 0; r < 4; r++) {
                int row = bm + 64 * wm + 16 * i + q * 4 + r;
                float v = acc[i][j][r];
                if (EPI == 5) {
                    if (!hside) {
                        v += bias[col];
                        Cf[(size_t)row * 256 + col] = v;
                    } else {
                        Cb[(size_t)row * 256 + (col - 256)] = f2b(v);
                    }
                }
            }
        }

    if (hside) {
        int head = 2 * ((int)blockIdx.y - 2) + wn;
        float as4[4], ad4[4];
#pragma unroll
        for (int j = 0; j < 4; j++) {
            as4[j] = a_s[head * 64 + 16 * j + lm];
            ad4[j] = a_d[head * 64 + 16 * j + lm];
        }
#pragma unroll
        for (int i = 0; i < 4; i++)
#pragma unroll
            for (int r = 0; r < 4; r++) {
                float ps = acc[i][0][r] * as4[0] + acc[i][1][r] * as4[1] +
                           acc[i][2][r] * as4[2] + acc[i][3][r] * as4[3];
                float pd = acc[i][0][r] * ad4[0] + acc[i][1][r] * ad4[1] +
                           acc[i][2][r] * ad4[2] + acc[i][3][r] * ad4[3];
#pragma unroll
                for (int off = 8; off > 0; off >>= 1) {
                    ps += __shfl_down(ps, off);
                    pd += __shfl_down(pd, off);
                }
                int row = bm + 64 * wm + 16 * i + q * 4 + r;
                if (lm == 0 && row < Nn) {
                    att_s[row * 4 + head] = ps;
                    att_d[row * 4 + head] = pd;
                }
            }
    }
}

// ---------------------------------------------------------------- GEMM 64x64
// EPI: 0 plain->bf16, 1 +bias->fp32, 2 relu(+bias)->bf16, 3 extraB*sigmoid(+bias)->bf16,
//      5 plain->bf16 + fused H=1 att dots (N must be 64).
template <int EPI, int K>
__global__ __launch_bounds__(256)
void gemm_kernel(const u16* __restrict__ A, const u16* __restrict__ Bt,
                 const float* __restrict__ bias, const u16* __restrict__ extraB,
                 float* __restrict__ Cf, u16* __restrict__ Cb,
                 const float* __restrict__ a_s, const float* __restrict__ a_d,
                 float* __restrict__ att_s, float* __restrict__ att_d, int Nn, int N) {
#define LDSS 40
    __shared__ u16 As[64 * LDSS];
    __shared__ u16 Bs[64 * LDSS];
    __shared__ float sps[64], spd[64];
    int t = threadIdx.x;
    int bm = blockIdx.x * 64, bn = blockIdx.y * 64;
    int w = t >> 6, lane = t & 63;
    int wm = w & 1, wn = w >> 1;
    int lm = lane & 15, q = lane >> 4;

    float4v acc[2][2];
#pragma unroll
    for (int i = 0; i < 2; i++)
#pragma unroll
        for (int j = 0; j < 2; j++) acc[i][j] = (float4v){0.f, 0.f, 0.f, 0.f};

    int ar = t >> 2;
    int ac = (t & 3) * 8;
    const u16* aPtr = A + (size_t)(bm + ar) * K + ac;
    const u16* bPtr = Bt + (size_t)(bn + ar) * K + ac;

#pragma unroll
    for (int k0 = 0; k0 < K; k0 += 32) {
        uint4 av = *(const uint4*)(aPtr + k0);
        uint4 bv = *(const uint4*)(bPtr + k0);
        *(uint4*)&As[ar * LDSS + ac] = av;
        *(uint4*)&Bs[ar * LDSS + ac] = bv;
        __syncthreads();

        short8 fa0 = *(const short8*)&As[(32 * wm + lm) * LDSS + q * 8];
        short8 fa1 = *(const short8*)&As[(32 * wm + 16 + lm) * LDSS + q * 8];
        short8 fb0 = *(const short8*)&Bs[(32 * wn + lm) * LDSS + q * 8];
        short8 fb1 = *(const short8*)&Bs[(32 * wn + 16 + lm) * LDSS + q * 8];
        acc[0][0] = __builtin_amdgcn_mfma_f32_16x16x32_bf16(fa0, fb0, acc[0][0], 0, 0, 0);
        acc[0][1] = __builtin_amdgcn_mfma_f32_16x16x32_bf16(fa0, fb1, acc[0][1], 0, 0, 0);
        acc[1][0] = __builtin_amdgcn_mfma_f32_16x16x32_bf16(fa1, fb0, acc[1][0], 0, 0, 0);
        acc[1][1] = __builtin_amdgcn_mfma_f32_16x16x32_bf16(fa1, fb1, acc[1][1], 0, 0, 0);
        __syncthreads();
    }

#pragma unroll
    for (int i = 0; i < 2; i++)
#pragma unroll
        for (int j = 0; j < 2; j++) {
            int col = bn + 32 * wn + 16 * j + lm;
            float bval = (EPI == 1 || EPI == 2 || EPI == 3) ? bias[col] : 0.f;
#pragma unroll
            for (int r = 0; r < 4; r++) {
                int row = bm + 32 * wm + 16 * i + q * 4 + r;
                float v = acc[i][j][r] + bval;
                if (EPI == 2) v = fmaxf(v, 0.f);
                if (EPI == 3) {
                    float xv = b2f(extraB[(size_t)row * N + col]);
                    v = xv / (1.f + __expf(-v));
                }
                size_t o = (size_t)row * N + col;
                if (EPI == 1) Cf[o] = v;
                else Cb[o] = f2b(v);
            }
        }

    if (EPI == 5) {
        // H=1 att dots: wave wn covers cols 32wn..32wn+31 of the single head.
        float as2[2], ad2[2];
#pragma unroll
        for (int j = 0; j < 2; j++) {
            as2[j] = a_s[32 * wn + 16 * j + lm];
            ad2[j] = a_d[32 * wn + 16 * j + lm];
        }
        float psv[8], pdv[8];
#pragma unroll
        for (int i = 0; i < 2; i++)
#pragma unroll
            for (int r = 0; r < 4; r++) {
                float ps = acc[i][0][r] * as2[0] + acc[i][1][r] * as2[1];
                float pd = acc[i][0][r] * ad2[0] + acc[i][1][r] * ad2[1];
#pragma unroll
                for (int off = 8; off > 0; off >>= 1) {
                    ps += __shfl_down(ps, off);
                    pd += __shfl_down(pd, off);
                }
                psv[i * 4 + r] = ps;
                pdv[i * 4 + r] = pd;
            }
        if (wn == 0 && lm == 0) {
#pragma unroll
            for (int i = 0; i < 2; i++)
#pragma unroll
                for (int r = 0; r < 4; r++) {
                    int rib = 32 * wm + 16 * i + 4 * q + r;
                    sps[rib] = psv[i * 4 + r];
                    spd[rib] = pdv[i * 4 + r];
                }
        }
        __syncthreads();
        if (wn == 1 && lm == 0) {
#pragma unroll
            for (int i = 0; i < 2; i++)
#pragma unroll
                for (int r = 0; r < 4; r++) {
                    int rib = 32 * wm + 16 * i + 4 * q + r;
                    int row = bm + rib;
                    if (row < Nn) {
                        att_s[row] = psv[i * 4 + r] + sps[rib];
                        att_d[row] = pdv[i * 4 + r] + spd[rib];
                    }
                }
        }
    }
}

// ---------------------------------------------------------------- GAT aggregate H=4
// One wave/node, 4-deep unrolled gather; qsum inline; self-loop at end.
__global__ __launch_bounds__(256)
void agg4_kernel(const uint2* __restrict__ hb2,  // [Nn][64] uint2 (256 bf16 ch)
                 const float* __restrict__ att_s, const float* __restrict__ att_d,
                 const int* __restrict__ row_ptr, const int2* __restrict__ csr2,
                 const float* __restrict__ ce_g, const float* __restrict__ bias,
                 const float* __restrict__ resid, u16* __restrict__ outb, int Nn) {
    int wv = __builtin_amdgcn_readfirstlane(threadIdx.x >> 6);
    int n = blockIdx.x * 4 + wv;
    if (n >= Nn) return;
    int lane = threadIdx.x & 63;
    int hh = lane >> 4;

    float ce = ce_g[hh];
    float adn = att_d[n * 4 + hh];
    float asn = att_s[n * 4 + hh];
    uint2 sv = hb2[(size_t)n * 64 + lane];
    float z = 0.f, qsum = 0.f;
    float aA0 = 0.f, aA1 = 0.f, aA2 = 0.f, aA3 = 0.f;
    float aB0 = 0.f, aB1 = 0.f, aB2 = 0.f, aB3 = 0.f;

    int e0 = row_ptr[n], e1 = row_ptr[n + 1];
    for (int base = e0; base < e1; base += 64) {
        int cnt = min(64, e1 - base);
        int2 cc = csr2[base + min(lane, cnt - 1)];
        int vsrc = cc.x;
        float vea = __int_as_float(cc.y);
        int i = 0;
        for (; i + 4 <= cnt; i += 4) {
            int sA = __shfl(vsrc, i),     sB = __shfl(vsrc, i + 1);
            int sC = __shfl(vsrc, i + 2), sD = __shfl(vsrc, i + 3);
            float qA = __shfl(vea, i),     qB = __shfl(vea, i + 1);
            float qC = __shfl(vea, i + 2), qD = __shfl(vea, i + 3);
            float gA = att_s[(u32)sA * 4u + hh], gB = att_s[(u32)sB * 4u + hh];
            float gC = att_s[(u32)sC * 4u + hh], gD = att_s[(u32)sD * 4u + hh];
            uint2 vA = hb2[(u32)sA * 64u + lane], vB = hb2[(u32)sB * 64u + lane];
            uint2 vC = hb2[(u32)sC * 64u + lane], vD = hb2[(u32)sD * 64u + lane];
            float pA = __expf(lrelu02(gA + adn + qA * ce));
            float pB = __expf(lrelu02(gB + adn + qB * ce));
            float pC = __expf(lrelu02(gC + adn + qC * ce));
            float pD = __expf(lrelu02(gD + adn + qD * ce));
            qsum += (qA + qB) + (qC + qD);
            z += (pA + pB) + (pC + pD);
            aA0 = fmaf(pA, lo2f(vA.x), aA0); aA1 = fmaf(pA, hi2f(vA.x), aA1);
            aA2 = fmaf(pA, lo2f(vA.y), aA2); aA3 = fmaf(pA, hi2f(vA.y), aA3);
            aB0 = fmaf(pB, lo2f(vB.x), aB0); aB1 = fmaf(pB, hi2f(vB.x), aB1);
            aB2 = fmaf(pB, lo2f(vB.y), aB2); aB3 = fmaf(pB, hi2f(vB.y), aB3);
            aA0 = fmaf(pC, lo2f(vC.x), aA0); aA1 = fmaf(pC, hi2f(vC.x), aA1);
            aA2 = fmaf(pC, lo2f(vC.y), aA2); aA3 = fmaf(pC, hi2f(vC.y), aA3);
            aB0 = fmaf(pD, lo2f(vD.x), aB0); aB1 = fmaf(pD, hi2f(vD.x), aB1);
            aB2 = fmaf(pD, lo2f(vD.y), aB2); aB3 = fmaf(pD, hi2f(vD.y), aB3);
        }
        for (; i < cnt; i++) {
            int s = __shfl(vsrc, i);
            float q = __shfl(vea, i);
            float g = att_s[(u32)s * 4u + hh];
            uint2 v = hb2[(u32)s * 64u + lane];
            float p = __expf(lrelu02(g + adn + q * ce));
            qsum += q;
            z += p;
            aA0 = fmaf(p, lo2f(v.x), aA0); aA1 = fmaf(p, hi2f(v.x), aA1);
            aA2 = fmaf(p, lo2f(v.y), aA2); aA3 = fmaf(p, hi2f(v.y), aA3);
        }
    }
    float la = qsum / (float)max(e1 - e0, 1);
    float ps = __expf(lrelu02(asn + adn + la * ce));
    z += ps;
    float a0 = aA0 + aB0 + ps * lo2f(sv.x);
    float a1 = aA1 + aB1 + ps * hi2f(sv.x);
    float a2 = aA2 + aB2 + ps * lo2f(sv.y);
    float a3 = aA3 + aB3 + ps * hi2f(sv.y);

    float inv = 1.f / z;
    int c0 = lane * 4;
    float4 bv = *(const float4*)&bias[c0];
    float4 rv = *(const float4*)&resid[(size_t)n * 256 + c0];
    float o0 = fmaf(a0, inv, bv.x);
    float o1 = fmaf(a1, inv, bv.y);
    float o2 = fmaf(a2, inv, bv.z);
    float o3 = fmaf(a3, inv, bv.w);
    o0 = fmaxf(o0, 0.01f * o0) + rv.x;
    o1 = fmaxf(o1, 0.01f * o1) + rv.y;
    o2 = fmaxf(o2, 0.01f * o2) + rv.z;
    o3 = fmaxf(o3, 0.01f * o3) + rv.w;
    uint2 packed;
    packed.x = ((u32)f2b(o0)) | (((u32)f2b(o1)) << 16);
    packed.y = ((u32)f2b(o2)) | (((u32)f2b(o3)) << 16);
    ((uint2*)outb)[(size_t)n * 64 + lane] = packed;
}

// ---------------------------------------------------------------- GAT aggregate H=1
__global__ __launch_bounds__(256)
void agg1_kernel(const uint2* __restrict__ hb2,  // [Nn][16] uint2 (64 bf16 ch)
                 const float* __restrict__ att_s, const float* __restrict__ att_d,
                 const int* __restrict__ row_ptr, const int2* __restrict__ csr2,
                 const float* __restrict__ ce_g, const float* __restrict__ bias,
                 const float* __restrict__ resid, float* __restrict__ outf, int Nn) {
    int wv = __builtin_amdgcn_readfirstlane(threadIdx.x >> 6);
    int n = blockIdx.x * 4 + wv;
    if (n >= Nn) return;
    int lane = threadIdx.x & 63;
    int qtr = lane >> 4;
    int cl = lane & 15;

    float ce = ce_g[8];
    float adn = att_d[n];
    float asn = att_s[n];
    uint2 sv = hb2[(u32)n * 16u + cl];
    float z = 0.f, qsum = 0.f;
    float a0 = 0.f, a1 = 0.f, a2 = 0.f, a3 = 0.f;

    int e0 = row_ptr[n], e1 = row_ptr[n + 1];
    for (int base = e0; base < e1; base += 64) {
        int cnt = min(64, e1 - base);
        int2 cc = csr2[base + min(lane, cnt - 1)];
        int vsrc = cc.x;
        float vea = __int_as_float(cc.y);
        for (int i = 0; i < cnt; i += 4) {
            int idx = min(i + qtr, cnt - 1);
            int s = __shfl(vsrc, idx);
            float q = __shfl(vea, idx);
            bool act = (i + qtr < cnt);
            float p = __expf(lrelu02(att_s[s] + adn + q * ce));
            p = act ? p : 0.f;
            q = act ? q : 0.f;
            uint2 v = hb2[(u32)s * 16u + cl];
            z += p;
            qsum += q;
            a0 = fmaf(p, lo2f(v.x), a0);
            a1 = fmaf(p, hi2f(v.x), a1);
            a2 = fmaf(p, lo2f(v.y), a2);
            a3 = fmaf(p, hi2f(v.y), a3);
        }
    }
    z += __shfl_xor(z, 16);       z += __shfl_xor(z, 32);
    qsum += __shfl_xor(qsum, 16); qsum += __shfl_xor(qsum, 32);
    a0 += __shfl_xor(a0, 16);     a0 += __shfl_xor(a0, 32);
    a1 += __shfl_xor(a1, 16);     a1 += __shfl_xor(a1, 32);
    a2 += __shfl_xor(a2, 16);     a2 += __shfl_xor(a2, 32);
    a3 += __shfl_xor(a3, 16);     a3 += __shfl_xor(a3, 32);

    float la = qsum / (float)max(e1 - e0, 1);
    float ps = __expf(lrelu02(asn + adn + la * ce));
    z += ps;
    a0 += ps * lo2f(sv.x);
    a1 += ps * hi2f(sv.x);
    a2 += ps * lo2f(sv.y);
    a3 += ps * hi2f(sv.y);

    if (lane < 16) {
        float inv = 1.f / z;
        int c0 = cl * 4;
        float4 bv = *(const float4*)&bias[c0];
        float4 rv = *(const float4*)&resid[(size_t)n * 64 + c0];
        float o0 = fmaf(a0, inv, bv.x);
        float o1 = fmaf(a1, inv, bv.y);
        float o2 = fmaf(a2, inv, bv.z);
        float o3 = fmaf(a3, inv, bv.w);
        o0 = fmaxf(o0, 0.01f * o0) + rv.x;
        o1 = fmaxf(o1, 0.01f * o1) + rv.y;
        o2 = fmaxf(o2, 0.01f * o2) + rv.z;
        o3 = fmaxf(o3, 0.01f * o3) + rv.w;
        *(float4*)&outf[(size_t)n * 64 + c0] = make_float4(o0, o1, o2, o3);
    }
}

// ---------------------------------------------------------------- launch
extern "C" void kernel_launch(void* const* d_in, const int* in_sizes, int n_in,
                              void* d_out, int out_size, void* d_ws, size_t ws_size,
                              hipStream_t stream) {
    const float* x    = (const float*)d_in[0];
    const int*   ei   = (const int*)d_in[1];
    const float* ea   = (const float*)d_in[2];
    const float* fa_w = (const float*)d_in[3];
    const float* fa_b = (const float*)d_in[4];
    const float* W1   = (const float*)d_in[5];
    const float* We1  = (const float*)d_in[6];
    const float* as1  = (const float*)d_in[7];
    const float* ad1  = (const float*)d_in[8];
    const float* ae1  = (const float*)d_in[9];
    const float* b1   = (const float*)d_in[10];
    const float* W2   = (const float*)d_in[11];
    const float* We2  = (const float*)d_in[12];
    const float* as2  = (const float*)d_in[13];
    const float* ad2  = (const float*)d_in[14];
    const float* ae2  = (const float*)d_in[15];
    const float* b2   = (const float*)d_in[16];
    const float* W3   = (const float*)d_in[17];
    const float* We3  = (const float*)d_in[18];
    const float* as3  = (const float*)d_in[19];
    const float* ad3  = (const float*)d_in[20];
    const float* ae3  = (const float*)d_in[21];
    const float* b3   = (const float*)d_in[22];
    const float* r1_w = (const float*)d_in[23];
    const float* r1_b = (const float*)d_in[24];
    const float* r2_w = (const float*)d_in[25];
    const float* r2_b = (const float*)d_in[26];
    const float* fw1  = (const float*)d_in[27];
    const float* fb1  = (const float*)d_in[28];
    const float* fw2  = (const float*)d_in[29];
    const float* fb2  = (const float*)d_in[30];

    const int Nn = in_sizes[0] / 128;
    const int E  = in_sizes[1] / 2;

    char* ws = (char*)d_ws;
    size_t off = 0;
    auto alloc = [&](size_t bytes) -> char* {
        char* p = ws + off;
        off += (bytes + 255) & ~((size_t)255);
        return p;
    };
    u32*   deg      = (u32*)alloc((size_t)Nn * 4);       // memset target
    u32*   rank     = (u32*)alloc((size_t)E * 4);
    int*   incl     = (int*)alloc((size_t)Nn * 4);
    int*   row_ptr  = (int*)alloc((size_t)(Nn + 1) * 4);
    int*   blocksum = (int*)alloc(1024);
    float* att_s    = (float*)alloc((size_t)(Nn + 128) * 16);
    float* att_d    = (float*)alloc((size_t)(Nn + 128) * 16);
    int2*  csr2     = (int2*)alloc((size_t)E * 8);
    float* ce_g     = (float*)alloc(64);
    u16* xbf   = (u16*)alloc((size_t)(Nn + 128) * 128 * 2);
    u16* xg_bf = (u16*)alloc((size_t)(Nn + 128) * 128 * 2);
    u16* h_bf  = (u16*)alloc((size_t)(Nn + 128) * 256 * 2);
    u16* z_bf  = (u16*)alloc((size_t)(Nn + 128) * 256 * 2);
    u16* mid_bf = (u16*)alloc((size_t)(Nn + 128) * 64 * 2);
    u16* h3_bf  = (u16*)alloc((size_t)(Nn + 128) * 64 * 2);
    u16* wt_fa = (u16*)alloc(16384 * 2);
    u16* wt_c1 = (u16*)alloc((size_t)512 * 128 * 2);
    u16* wt_c2 = (u16*)alloc((size_t)512 * 256 * 2);
    u16* wt_W3 = (u16*)alloc(16384 * 2);
    u16* wt_f1 = (u16*)alloc(8192 * 2);
    u16* wt_f2 = (u16*)alloc(4096 * 2);
    float* residB = (float*)alloc((size_t)(Nn + 128) * 256 * 4);
    float* zself  = (float*)alloc((size_t)(Nn + 128) * 64 * 4);

    hipMemsetAsync(deg, 0, (size_t)Nn * 4, stream);

    int eb = (E + 255) / 256;       // 3125
    int nb = (Nn + 255) / 256;      // 196 (<= 256 for scan_final)
    int n4 = Nn * 128 / 4;
    int xb4 = (n4 + 255) / 256;     // 6250

    prep_mega<<<dim3(max(xb4, eb), 3), 256, 0, stream>>>(
        x, xbf, n4,
        fa_w, r1_w, W1, r2_w, W2, W3, fw1, fw2,
        wt_fa, wt_c1, wt_c1 + (size_t)256 * 128, wt_c2, wt_c2 + (size_t)256 * 256,
        wt_W3, wt_f1, wt_f2, We1, ae1, We2, ae2, We3, ae3, ce_g,
        ei, deg, rank, E);
    scan_block_kernel<<<nb, 256, 0, stream>>>(deg, incl, blocksum, Nn);
    scan_final_kernel<<<nb, 256, 0, stream>>>(deg, incl, blocksum, row_ptr, Nn);
    scatter_kernel<<<eb, 256, 0, stream>>>(ei, ea, row_ptr, rank, csr2, E);

    int mb  = (Nn + 63) / 64;     // 782
    int mb1 = (Nn + 127) / 128;   // 391
    int ab  = (Nn + 3) / 4;       // 12500

    // xg = x * sigmoid(x@fa_w + fa_b)
    gemm_kernel<3, 128><<<dim3(mb, 2), 256, 0, stream>>>(
        xbf, wt_fa, fa_b, xbf, nullptr, xg_bf, nullptr, nullptr, nullptr, nullptr, Nn, 128);
    // fused: [xr1 | h1] + att1 dots
    gemm128_kernel<5, 128><<<dim3(mb1, 4), 256, 0, stream>>>(
        xg_bf, wt_c1, r1_b, residB, h_bf, as1, ad1, att_s, att_d, Nn);
    agg4_kernel<<<ab, 256, 0, stream>>>((const uint2*)h_bf, att_s, att_d, row_ptr, csr2,
                                        ce_g, b1, residB, z_bf, Nn);
    // fused: [xr2 | h2] + att2 dots
    gemm128_kernel<5, 256><<<dim3(mb1, 4), 256, 0, stream>>>(
        z_bf, wt_c2, r2_b, residB, h_bf, as2, ad2, att_s, att_d, Nn);
    agg4_kernel<<<ab, 256, 0, stream>>>((const uint2*)h_bf, att_s, att_d, row_ptr, csr2,
                                        ce_g + 4, b2, residB, z_bf, Nn);
    // z_self = relu(xg@fw1+fb1)@fw2 + fb2
    gemm_kernel<2, 128><<<dim3(mb, 1), 256, 0, stream>>>(
        xg_bf, wt_f1, fb1, nullptr, nullptr, mid_bf, nullptr, nullptr, nullptr, nullptr, Nn, 64);
    gemm_kernel<1, 64><<<dim3(mb, 1), 256, 0, stream>>>(
        mid_bf, wt_f2, fb2, nullptr, zself, nullptr, nullptr, nullptr, nullptr, nullptr, Nn, 64);
    // h3 = z2@W3 + att3 dots (H=1)
    gemm_kernel<5, 256><<<dim3(mb, 1), 256, 0, stream>>>(
        z_bf, wt_W3, nullptr, nullptr, nullptr, h3_bf, as3, ad3, att_s, att_d, Nn, 64);
    agg1_kernel<<<ab, 256, 0, stream>>>((const uint2*)h3_bf, att_s, att_d, row_ptr, csr2,
                                        ce_g, b3, zself, (float*)d_out, Nn);
}

// Round 10
// 494.762 us; speedup vs baseline: 1.0319x; 1.0319x over previous
//
#include <hip/hip_runtime.h>
#include <hip/hip_bf16.h>

// GATNodeEdgePrediction on MI355X (gfx950) — Round 10.
//  - REVERTED round-9 att fusion (regressed: epilogue shuffle trees cost more
//    in-GEMM than the standalone streaming att kernels). att4/att1 restored.
//  - agg4 kept at 4-deep unroll (VGPR 28, ~70% occupancy — round-9 win).
//  - Residual (xr1/xr2) and zself buffers now bf16: ~25 MB fewer epilogue
//    writes + ~26 MB fewer agg reads. absmax budget: +~1e-3, still << 0.0108.
//  - f1 folded into c1: wt_c1 = [r1|W1|fw1] (640x128), grid (391,5), region
//    epilogue (resid+bias / h / relu+bias->mid). One dispatch fewer.

typedef unsigned short u16;
typedef unsigned int   u32;
typedef __attribute__((ext_vector_type(8))) short short8;
typedef __attribute__((ext_vector_type(4))) float float4v;

typedef const __attribute__((address_space(1))) u32* gptr_t;
typedef __attribute__((address_space(3))) u32* lptr_t;
#define GLOAD_LDS16(g, l) \
    __builtin_amdgcn_global_load_lds((gptr_t)(const void*)(g), (lptr_t)(void*)(l), 16, 0, 0)

static __device__ __forceinline__ u16 f2b(float f) {
    u32 u = __float_as_uint(f);
    u32 r = u + 0x7fffu + ((u >> 16) & 1u);  // RNE
    return (u16)(r >> 16);
}
static __device__ __forceinline__ float b2f(u16 u) {
    return __uint_as_float(((u32)u) << 16);
}
static __device__ __forceinline__ float lo2f(u32 v) { return __uint_as_float(v << 16); }
static __device__ __forceinline__ float hi2f(u32 v) { return __uint_as_float(v & 0xffff0000u); }
static __device__ __forceinline__ float lrelu02(float x) { return fmaxf(x, 0.2f * x); }

// ---------------------------------------------------------------- merged prep
__global__ void prep_mega(const float* __restrict__ x, u16* __restrict__ xb, int n4,
                          const float* s0, const float* s1, const float* s2,
                          const float* s3, const float* s4, const float* s5,
                          const float* s6, const float* s7,
                          u16* d0, u16* d1, u16* d2, u16* d3,
                          u16* d4, u16* d5, u16* d6, u16* d7,
                          const float* We1, const float* ae1,
                          const float* We2, const float* ae2,
                          const float* We3, const float* ae3, float* ce_g,
                          const int* __restrict__ ei,
                          u32* deg, u32* rank, int E) {
    int role = blockIdx.y;
    if (role == 0) {
        int i = blockIdx.x * 256 + threadIdx.x;
        if (i >= n4) return;
        float4 v = ((const float4*)x)[i];
        ushort4 o;
        o.x = f2b(v.x); o.y = f2b(v.y); o.z = f2b(v.z); o.w = f2b(v.w);
        ((ushort4*)xb)[i] = o;
    } else if (role == 2) {
        int e = blockIdx.x * 256 + threadIdx.x;
        if (e >= E) return;
        int d = ei[E + e];
        rank[e] = atomicAdd(&deg[d], 1u);
    } else {
        int wid = blockIdx.x >> 4, sub = blockIdx.x & 15;
        if (wid > 8) return;
        if (wid == 8) {
            if (sub == 0) {
                int t = threadIdx.x;
                if (t < 9) {
                    const float* W; const float* a; int h;
                    if (t < 4)      { W = We1; a = ae1; h = t; }
                    else if (t < 8) { W = We2; a = ae2; h = t - 4; }
                    else            { W = We3; a = ae3; h = 0; }
                    float s = 0.f;
                    for (int c = 0; c < 64; c++) s += W[h * 64 + c] * a[h * 64 + c];
                    ce_g[t] = s;
                }
            }
            return;
        }
        const float* src; u16* dst; int K, N;
        switch (wid) {
            case 0: src = s0; dst = d0; K = 128; N = 128; break;
            case 1: src = s1; dst = d1; K = 128; N = 256; break;
            case 2: src = s2; dst = d2; K = 128; N = 256; break;
            case 3: src = s3; dst = d3; K = 256; N = 256; break;
            case 4: src = s4; dst = d4; K = 256; N = 256; break;
            case 5: src = s5; dst = d5; K = 256; N = 64;  break;
            case 6: src = s6; dst = d6; K = 128; N = 64;  break;
            default: src = s7; dst = d7; K = 64;  N = 64;  break;
        }
        int KN = K * N;
        int nmask = N - 1;
        int nshift = __popc((u32)nmask);
        for (int i = sub * 256 + threadIdx.x; i < KN; i += 16 * 256) {
            int k = i >> nshift, n2 = i & nmask;
            dst[(size_t)n2 * K + k] = f2b(src[i]);
        }
    }
}

// ---------------------------------------------------------------- CSR build
__global__ void scan_block_kernel(const u32* __restrict__ deg, int* incl,
                                  int* blocksum, int Nn) {
    __shared__ int sb[256];
    int t = threadIdx.x;
    int n = blockIdx.x * 256 + t;
    int v = (n < Nn) ? (int)deg[n] : 0;
    sb[t] = v;
    __syncthreads();
    for (int off = 1; off < 256; off <<= 1) {
        int x = (t >= off) ? sb[t - off] : 0;
        __syncthreads();
        sb[t] += x;
        __syncthreads();
    }
    if (n < Nn) incl[n] = sb[t];
    if (t == 255) blocksum[blockIdx.x] = sb[255];
}

__global__ void scan_final_kernel(const u32* __restrict__ deg, const int* __restrict__ incl,
                                  const int* __restrict__ blocksum,
                                  int* row_ptr, int Nn) {
    __shared__ int sb[256];
    int t = threadIdx.x;
    int b = blockIdx.x;
    sb[t] = (t < b) ? blocksum[t] : 0;   // gridDim <= 256
    __syncthreads();
    for (int off = 128; off > 0; off >>= 1) {
        if (t < off) sb[t] += sb[t + off];
        __syncthreads();
    }
    int base = sb[0];
    int n = b * 256 + t;
    if (n >= Nn) return;
    int d = (int)deg[n];
    int excl = base + incl[n] - d;
    row_ptr[n] = excl;
    if (n == Nn - 1) row_ptr[Nn] = excl + d;
}

__global__ void scatter_kernel(const int* __restrict__ ei, const float* __restrict__ ea,
                               const int* __restrict__ row_ptr, const u32* __restrict__ rank,
                               int2* __restrict__ csr2, int E) {
    int e = blockIdx.x * 256 + threadIdx.x;
    if (e >= E) return;
    int d = ei[E + e];
    int pos = row_ptr[d] + (int)rank[e];
    csr2[pos] = make_int2(ei[e], __float_as_int(ea[e]));
}

// ---------------------------------------------------------------- GEMM 128x128
// EPI 4 (N=512): col<256 -> bf16 resid (+bias1); col>=256 -> bf16 h.
// EPI 6 (N=640): + cols 512..575 -> bf16 mid = relu(v + bias2); 576+ skipped.
// Unguarded loads AND stores (+128-row slack buffers).
template <int EPI, int K>
__global__ __launch_bounds__(256)
void gemm128_kernel(const u16* __restrict__ A, const u16* __restrict__ Bt,
                    const float* __restrict__ bias1, const float* __restrict__ bias2,
                    u16* __restrict__ Cres, u16* __restrict__ Ch, u16* __restrict__ Cmid) {
    __shared__ u16 As[128 * 32];
    __shared__ u16 Bs[128 * 32];
    int t = threadIdx.x;
    int w = t >> 6, lane = t & 63;
    int wm = w & 1, wn = w >> 1;
    int lm = lane & 15, q = lane >> 4;
    int bm = blockIdx.x * 128, bn = blockIdx.y * 128;

    float4v acc[4][4];
#pragma unroll
    for (int i = 0; i < 4; i++)
#pragma unroll
        for (int j = 0; j < 4; j++) acc[i][j] = (float4v){0.f, 0.f, 0.f, 0.f};

    int srow = lane >> 2;
    int scol = (lane & 3) * 8;
    const u16* aG = A + (size_t)(bm + w * 32 + srow) * K + scol;
    const u16* bG = Bt + (size_t)(bn + w * 32 + srow) * K + scol;
    u16* aL0 = &As[(w * 32) * 32];
    u16* aL1 = &As[(w * 32 + 16) * 32];
    u16* bL0 = &Bs[(w * 32) * 32];
    u16* bL1 = &Bs[(w * 32 + 16) * 32];

#pragma unroll
    for (int k0 = 0; k0 < K; k0 += 32) {
        GLOAD_LDS16(aG + k0, aL0);
        GLOAD_LDS16(aG + (size_t)16 * K + k0, aL1);
        GLOAD_LDS16(bG + k0, bL0);
        GLOAD_LDS16(bG + (size_t)16 * K + k0, bL1);
        __syncthreads();

        short8 af[4], bf[4];
#pragma unroll
        for (int i = 0; i < 4; i++)
            af[i] = *(const short8*)&As[(64 * wm + 16 * i + lm) * 32 + q * 8];
#pragma unroll
        for (int j = 0; j < 4; j++)
            bf[j] = *(const short8*)&Bs[(64 * wn + 16 * j + lm) * 32 + q * 8];
#pragma unroll
        for (int i = 0; i < 4; i++)
#pragma unroll
            for (int j = 0; j < 4; j++)
                acc[i][j] = __builtin_amdgcn_mfma_f32_16x16x32_bf16(af[i], bf[j], acc[i][j], 0, 0, 0);
        __syncthreads();
    }

#pragma unroll
    for (int i = 0; i < 4; i++)
#pragma unroll
        for (int j = 0; j < 4; j++) {
            int col = bn + 64 * wn + 16 * j + lm;
#pragma unroll
            for (int r = 0; r < 4; r++) {
                int row = bm + 64 * wm + 16 * i + q * 4 + r;
                float v = acc[i][j][r];
                if (col < 256) {
                    Cres[(size_t)row * 256 + col] = f2b(v + bias1[col]);
                } else if (EPI == 4 || col < 512) {
                    Ch[(size_t)row * 256 + (col - 256)] = f2b(v);
                } else if (col < 576) {
                    Cmid[(size_t)row * 64 + (col - 512)] = f2b(fmaxf(v + bias2[col - 512], 0.f));
                }
            }
        }
}

// ---------------------------------------------------------------- GEMM 64x64
// EPI: 0 plain->bf16, 1 +bias->bf16, 3 extraB*sigmoid(+bias)->bf16.
template <int EPI, int K>
__global__ __launch_bounds__(256)
void gemm_kernel(const u16* __restrict__ A, const u16* __restrict__ Bt,
                 const float* __restrict__ bias, const u16* __restrict__ extraB,
                 u16* __restrict__ Cb, int N) {
#define LDSS 40
    __shared__ u16 As[64 * LDSS];
    __shared__ u16 Bs[64 * LDSS];
    int t = threadIdx.x;
    int bm = blockIdx.x * 64, bn = blockIdx.y * 64;
    int w = t >> 6, lane = t & 63;
    int wm = w & 1, wn = w >> 1;
    int lm = lane & 15, q = lane >> 4;

    float4v acc[2][2];
#pragma unroll
    for (int i = 0; i < 2; i++)
#pragma unroll
        for (int j = 0; j < 2; j++) acc[i][j] = (float4v){0.f, 0.f, 0.f, 0.f};

    int ar = t >> 2;
    int ac = (t & 3) * 8;
    const u16* aPtr = A + (size_t)(bm + ar) * K + ac;
    const u16* bPtr = Bt + (size_t)(bn + ar) * K + ac;

#pragma unroll
    for (int k0 = 0; k0 < K; k0 += 32) {
        uint4 av = *(const uint4*)(aPtr + k0);
        uint4 bv = *(const uint4*)(bPtr + k0);
        *(uint4*)&As[ar * LDSS + ac] = av;
        *(uint4*)&Bs[ar * LDSS + ac] = bv;
        __syncthreads();

        short8 fa0 = *(const short8*)&As[(32 * wm + lm) * LDSS + q * 8];
        short8 fa1 = *(const short8*)&As[(32 * wm + 16 + lm) * LDSS + q * 8];
        short8 fb0 = *(const short8*)&Bs[(32 * wn + lm) * LDSS + q * 8];
        short8 fb1 = *(const short8*)&Bs[(32 * wn + 16 + lm) * LDSS + q * 8];
        acc[0][0] = __builtin_amdgcn_mfma_f32_16x16x32_bf16(fa0, fb0, acc[0][0], 0, 0, 0);
        acc[0][1] = __builtin_amdgcn_mfma_f32_16x16x32_bf16(fa0, fb1, acc[0][1], 0, 0, 0);
        acc[1][0] = __builtin_amdgcn_mfma_f32_16x16x32_bf16(fa1, fb0, acc[1][0], 0, 0, 0);
        acc[1][1] = __builtin_amdgcn_mfma_f32_16x16x32_bf16(fa1, fb1, acc[1][1], 0, 0, 0);
        __syncthreads();
    }

#pragma unroll
    for (int i = 0; i < 2; i++)
#pragma unroll
        for (int j = 0; j < 2; j++) {
            int col = bn + 32 * wn + 16 * j + lm;
            float bval = (EPI >= 1) ? bias[col] : 0.f;
#pragma unroll
            for (int r = 0; r < 4; r++) {
                int row = bm + 32 * wm + 16 * i + q * 4 + r;
                float v = acc[i][j][r] + bval;
                if (EPI == 3) {
                    float xv = b2f(extraB[(size_t)row * N + col]);
                    v = xv / (1.f + __expf(-v));
                }
                Cb[(size_t)row * N + col] = f2b(v);
            }
        }
}

// ---------------------------------------------------------------- attention dots
__global__ __launch_bounds__(256)
void att4_kernel(const uint2* __restrict__ hb2, const float* __restrict__ a_s,
                 const float* __restrict__ a_d, float* att_s, float* att_d, int Nn) {
    int wv = threadIdx.x >> 6;
    int n = blockIdx.x * 4 + wv;
    if (n >= Nn) return;
    int lane = threadIdx.x & 63;
    float4 as4 = *(const float4*)&a_s[lane * 4];
    float4 ad4 = *(const float4*)&a_d[lane * 4];
    uint2 v = hb2[(size_t)n * 64 + lane];
    float c0 = lo2f(v.x), c1 = hi2f(v.x), c2 = lo2f(v.y), c3 = hi2f(v.y);
    float ps = c0 * as4.x + c1 * as4.y + c2 * as4.z + c3 * as4.w;
    float pd = c0 * ad4.x + c1 * ad4.y + c2 * ad4.z + c3 * ad4.w;
#pragma unroll
    for (int off = 8; off > 0; off >>= 1) {
        ps += __shfl_down(ps, off);
        pd += __shfl_down(pd, off);
    }
    if ((lane & 15) == 0) {
        att_s[n * 4 + (lane >> 4)] = ps;
        att_d[n * 4 + (lane >> 4)] = pd;
    }
}

__global__ __launch_bounds__(256)
void att1_kernel(const u32* __restrict__ hb, const float* __restrict__ a_s,
                 const float* __restrict__ a_d, float* att_s, float* att_d, int Nn) {
    int wv = threadIdx.x >> 6;
    int n = blockIdx.x * 4 + wv;
    if (n >= Nn) return;
    int lane = threadIdx.x & 63;
    int cl = lane & 31;
    float2 as2 = *(const float2*)&a_s[cl * 2];
    float2 ad2 = *(const float2*)&a_d[cl * 2];
    u32 v = hb[(u32)n * 32u + cl];
    float c0 = lo2f(v), c1 = hi2f(v);
    float ps = c0 * as2.x + c1 * as2.y;
    float pd = c0 * ad2.x + c1 * ad2.y;
    if (lane >= 32) { ps = 0.f; pd = 0.f; }
#pragma unroll
    for (int off = 16; off > 0; off >>= 1) {
        ps += __shfl_down(ps, off);
        pd += __shfl_down(pd, off);
    }
    if (lane == 0) {
        att_s[n] = ps;
        att_d[n] = pd;
    }
}

// ---------------------------------------------------------------- GAT aggregate H=4
// One wave/node, 4-deep unrolled gather; qsum inline; self-loop at end.
__global__ __launch_bounds__(256)
void agg4_kernel(const uint2* __restrict__ hb2,  // [Nn][64] uint2 (256 bf16 ch)
                 const float* __restrict__ att_s, const float* __restrict__ att_d,
                 const int* __restrict__ row_ptr, const int2* __restrict__ csr2,
                 const float* __restrict__ ce_g, const float* __restrict__ bias,
                 const uint2* __restrict__ resid2, u16* __restrict__ outb, int Nn) {
    int wv = __builtin_amdgcn_readfirstlane(threadIdx.x >> 6);
    int n = blockIdx.x * 4 + wv;
    if (n >= Nn) return;
    int lane = threadIdx.x & 63;
    int hh = lane >> 4;

    float ce = ce_g[hh];
    float adn = att_d[n * 4 + hh];
    float asn = att_s[n * 4 + hh];
    uint2 sv = hb2[(size_t)n * 64 + lane];
    float z = 0.f, qsum = 0.f;
    float aA0 = 0.f, aA1 = 0.f, aA2 = 0.f, aA3 = 0.f;
    float aB0 = 0.f, aB1 = 0.f, aB2 = 0.f, aB3 = 0.f;

    int e0 = row_ptr[n], e1 = row_ptr[n + 1];
    for (int base = e0; base < e1; base += 64) {
        int cnt = min(64, e1 - base);
        int2 cc = csr2[base + min(lane, cnt - 1)];
        int vsrc = cc.x;
        float vea = __int_as_float(cc.y);
        int i = 0;
        for (; i + 4 <= cnt; i += 4) {
            int sA = __shfl(vsrc, i),     sB = __shfl(vsrc, i + 1);
            int sC = __shfl(vsrc, i + 2), sD = __shfl(vsrc, i + 3);
            float qA = __shfl(vea, i),     qB = __shfl(vea, i + 1);
            float qC = __shfl(vea, i + 2), qD = __shfl(vea, i + 3);
            float gA = att_s[(u32)sA * 4u + hh], gB = att_s[(u32)sB * 4u + hh];
            float gC = att_s[(u32)sC * 4u + hh], gD = att_s[(u32)sD * 4u + hh];
            uint2 vA = hb2[(u32)sA * 64u + lane], vB = hb2[(u32)sB * 64u + lane];
            uint2 vC = hb2[(u32)sC * 64u + lane], vD = hb2[(u32)sD * 64u + lane];
            float pA = __expf(lrelu02(gA + adn + qA * ce));
            float pB = __expf(lrelu02(gB + adn + qB * ce));
            float pC = __expf(lrelu02(gC + adn + qC * ce));
            float pD = __expf(lrelu02(gD + adn + qD * ce));
            qsum += (qA + qB) + (qC + qD);
            z += (pA + pB) + (pC + pD);
            aA0 = fmaf(pA, lo2f(vA.x), aA0); aA1 = fmaf(pA, hi2f(vA.x), aA1);
            aA2 = fmaf(pA, lo2f(vA.y), aA2); aA3 = fmaf(pA, hi2f(vA.y), aA3);
            aB0 = fmaf(pB, lo2f(vB.x), aB0); aB1 = fmaf(pB, hi2f(vB.x), aB1);
            aB2 = fmaf(pB, lo2f(vB.y), aB2); aB3 = fmaf(pB, hi2f(vB.y), aB3);
            aA0 = fmaf(pC, lo2f(vC.x), aA0); aA1 = fmaf(pC, hi2f(vC.x), aA1);
            aA2 = fmaf(pC, lo2f(vC.y), aA2); aA3 = fmaf(pC, hi2f(vC.y), aA3);
            aB0 = fmaf(pD, lo2f(vD.x), aB0); aB1 = fmaf(pD, hi2f(vD.x), aB1);
            aB2 = fmaf(pD, lo2f(vD.y), aB2); aB3 = fmaf(pD, hi2f(vD.y), aB3);
        }
        for (; i < cnt; i++) {
            int s = __shfl(vsrc, i);
            float q = __shfl(vea, i);
            float g = att_s[(u32)s * 4u + hh];
            uint2 v = hb2[(u32)s * 64u + lane];
            float p = __expf(lrelu02(g + adn + q * ce));
            qsum += q;
            z += p;
            aA0 = fmaf(p, lo2f(v.x), aA0); aA1 = fmaf(p, hi2f(v.x), aA1);
            aA2 = fmaf(p, lo2f(v.y), aA2); aA3 = fmaf(p, hi2f(v.y), aA3);
        }
    }
    float la = qsum / (float)max(e1 - e0, 1);
    float ps = __expf(lrelu02(asn + adn + la * ce));
    z += ps;
    float a0 = aA0 + aB0 + ps * lo2f(sv.x);
    float a1 = aA1 + aB1 + ps * hi2f(sv.x);
    float a2 = aA2 + aB2 + ps * lo2f(sv.y);
    float a3 = aA3 + aB3 + ps * hi2f(sv.y);

    float inv = 1.f / z;
    int c0 = lane * 4;
    float4 bv = *(const float4*)&bias[c0];
    uint2 rr = resid2[(size_t)n * 64 + lane];
    float o0 = fmaf(a0, inv, bv.x);
    float o1 = fmaf(a1, inv, bv.y);
    float o2 = fmaf(a2, inv, bv.z);
    float o3 = fmaf(a3, inv, bv.w);
    o0 = fmaxf(o0, 0.01f * o0) + lo2f(rr.x);
    o1 = fmaxf(o1, 0.01f * o1) + hi2f(rr.x);
    o2 = fmaxf(o2, 0.01f * o2) + lo2f(rr.y);
    o3 = fmaxf(o3, 0.01f * o3) + hi2f(rr.y);
    uint2 packed;
    packed.x = ((u32)f2b(o0)) | (((u32)f2b(o1)) << 16);
    packed.y = ((u32)f2b(o2)) | (((u32)f2b(o3)) << 16);
    ((uint2*)outb)[(size_t)n * 64 + lane] = packed;
}

// ---------------------------------------------------------------- GAT aggregate H=1
__global__ __launch_bounds__(256)
void agg1_kernel(const uint2* __restrict__ hb2,  // [Nn][16] uint2 (64 bf16 ch)
                 const float* __restrict__ att_s, const float* __restrict__ att_d,
                 const int* __restrict__ row_ptr, const int2* __restrict__ csr2,
                 const float* __restrict__ ce_g, const float* __restrict__ bias,
                 const uint2* __restrict__ zs2, float* __restrict__ outf, int Nn) {
    int wv = __builtin_amdgcn_readfirstlane(threadIdx.x >> 6);
    int n = blockIdx.x * 4 + wv;
    if (n >= Nn) return;
    int lane = threadIdx.x & 63;
    int qtr = lane >> 4;
    int cl = lane & 15;

    float ce = ce_g[8];
    float adn = att_d[n];
    float asn = att_s[n];
    uint2 sv = hb2[(u32)n * 16u + cl];
    float z = 0.f, qsum = 0.f;
    float a0 = 0.f, a1 = 0.f, a2 = 0.f, a3 = 0.f;

    int e0 = row_ptr[n], e1 = row_ptr[n + 1];
    for (int base = e0; base < e1; base += 64) {
        int cnt = min(64, e1 - base);
        int2 cc = csr2[base + min(lane, cnt - 1)];
        int vsrc = cc.x;
        float vea = __int_as_float(cc.y);
        for (int i = 0; i < cnt; i += 4) {
            int idx = min(i + qtr, cnt - 1);
            int s = __shfl(vsrc, idx);
            float q = __shfl(vea, idx);
            bool act = (i + qtr < cnt);
            float p = __expf(lrelu02(att_s[s] + adn + q * ce));
            p = act ? p : 0.f;
            q = act ? q : 0.f;
            uint2 v = hb2[(u32)s * 16u + cl];
            z += p;
            qsum += q;
            a0 = fmaf(p, lo2f(v.x), a0);
            a1 = fmaf(p, hi2f(v.x), a1);
            a2 = fmaf(p, lo2f(v.y), a2);
            a3 = fmaf(p, hi2f(v.y), a3);
        }
    }
    z += __shfl_xor(z, 16);       z += __shfl_xor(z, 32);
    qsum += __shfl_xor(qsum, 16); qsum += __shfl_xor(qsum, 32);
    a0 += __shfl_xor(a0, 16);     a0 += __shfl_xor(a0, 32);
    a1 += __shfl_xor(a1, 16);     a1 += __shfl_xor(a1, 32);
    a2 += __shfl_xor(a2, 16);     a2 += __shfl_xor(a2, 32);
    a3 += __shfl_xor(a3, 16);     a3 += __shfl_xor(a3, 32);

    float la = qsum / (float)max(e1 - e0, 1);
    float ps = __expf(lrelu02(asn + adn + la * ce));
    z += ps;
    a0 += ps * lo2f(sv.x);
    a1 += ps * hi2f(sv.x);
    a2 += ps * lo2f(sv.y);
    a3 += ps * hi2f(sv.y);

    if (lane < 16) {
        float inv = 1.f / z;
        int c0 = cl * 4;
        float4 bv = *(const float4*)&bias[c0];
        uint2 zz = zs2[(u32)n * 16u + cl];
        float o0 = fmaf(a0, inv, bv.x);
        float o1 = fmaf(a1, inv, bv.y);
        float o2 = fmaf(a2, inv, bv.z);
        float o3 = fmaf(a3, inv, bv.w);
        o0 = fmaxf(o0, 0.01f * o0) + lo2f(zz.x);
        o1 = fmaxf(o1, 0.01f * o1) + hi2f(zz.x);
        o2 = fmaxf(o2, 0.01f * o2) + lo2f(zz.y);
        o3 = fmaxf(o3, 0.01f * o3) + hi2f(zz.y);
        *(float4*)&outf[(size_t)n * 64 + c0] = make_float4(o0, o1, o2, o3);
    }
}

// ---------------------------------------------------------------- launch
extern "C" void kernel_launch(void* const* d_in, const int* in_sizes, int n_in,
                              void* d_out, int out_size, void* d_ws, size_t ws_size,
                              hipStream_t stream) {
    const float* x    = (const float*)d_in[0];
    const int*   ei   = (const int*)d_in[1];
    const float* ea   = (const float*)d_in[2];
    const float* fa_w = (const float*)d_in[3];
    const float* fa_b = (const float*)d_in[4];
    const float* W1   = (const float*)d_in[5];
    const float* We1  = (const float*)d_in[6];
    const float* as1  = (const float*)d_in[7];
    const float* ad1  = (const float*)d_in[8];
    const float* ae1  = (const float*)d_in[9];
    const float* b1   = (const float*)d_in[10];
    const float* W2   = (const float*)d_in[11];
    const float* We2  = (const float*)d_in[12];
    const float* as2  = (const float*)d_in[13];
    const float* ad2  = (const float*)d_in[14];
    const float* ae2  = (const float*)d_in[15];
    const float* b2   = (const float*)d_in[16];
    const float* W3   = (const float*)d_in[17];
    const float* We3  = (const float*)d_in[18];
    const float* as3  = (const float*)d_in[19];
    const float* ad3  = (const float*)d_in[20];
    const float* ae3  = (const float*)d_in[21];
    const float* b3   = (const float*)d_in[22];
    const float* r1_w = (const float*)d_in[23];
    const float* r1_b = (const float*)d_in[24];
    const float* r2_w = (const float*)d_in[25];
    const float* r2_b = (const float*)d_in[26];
    const float* fw1  = (const float*)d_in[27];
    const float* fb1  = (const float*)d_in[28];
    const float* fw2  = (const float*)d_in[29];
    const float* fb2  = (const float*)d_in[30];

    const int Nn = in_sizes[0] / 128;
    const int E  = in_sizes[1] / 2;

    char* ws = (char*)d_ws;
    size_t off = 0;
    auto alloc = [&](size_t bytes) -> char* {
        char* p = ws + off;
        off += (bytes + 255) & ~((size_t)255);
        return p;
    };
    u32*   deg      = (u32*)alloc((size_t)Nn * 4);       // memset target
    u32*   rank     = (u32*)alloc((size_t)E * 4);
    int*   incl     = (int*)alloc((size_t)Nn * 4);
    int*   row_ptr  = (int*)alloc((size_t)(Nn + 1) * 4);
    int*   blocksum = (int*)alloc(1024);
    float* att_s    = (float*)alloc((size_t)Nn * 16);
    float* att_d    = (float*)alloc((size_t)Nn * 16);
    int2*  csr2     = (int2*)alloc((size_t)E * 8);
    float* ce_g     = (float*)alloc(64);
    u16* xbf   = (u16*)alloc((size_t)(Nn + 128) * 128 * 2);
    u16* xg_bf = (u16*)alloc((size_t)(Nn + 128) * 128 * 2);
    u16* h_bf  = (u16*)alloc((size_t)(Nn + 128) * 256 * 2);
    u16* z_bf  = (u16*)alloc((size_t)(Nn + 128) * 256 * 2);
    u16* mid_bf = (u16*)alloc((size_t)(Nn + 128) * 64 * 2);
    u16* h3_bf  = (u16*)alloc((size_t)(Nn + 128) * 64 * 2);
    u16* wt_fa = (u16*)alloc(16384 * 2);
    u16* wt_c1 = (u16*)alloc((size_t)640 * 128 * 2);   // [r1 | W1 | fw1 | 64 pad rows]
    u16* wt_c2 = (u16*)alloc((size_t)512 * 256 * 2);   // [r2 | W2]
    u16* wt_W3 = (u16*)alloc(16384 * 2);
    u16* wt_f2 = (u16*)alloc(4096 * 2);
    u16* residB = (u16*)alloc((size_t)(Nn + 128) * 256 * 2);  // bf16 residuals
    u16* zself  = (u16*)alloc((size_t)(Nn + 128) * 64 * 2);   // bf16 z_self

    hipMemsetAsync(deg, 0, (size_t)Nn * 4, stream);

    int eb = (E + 255) / 256;       // 3125
    int nb = (Nn + 255) / 256;      // 196 (<= 256 for scan_final)
    int n4 = Nn * 128 / 4;
    int xb4 = (n4 + 255) / 256;     // 6250

    prep_mega<<<dim3(max(xb4, eb), 3), 256, 0, stream>>>(
        x, xbf, n4,
        fa_w, r1_w, W1, r2_w, W2, W3, fw1, fw2,
        wt_fa, wt_c1, wt_c1 + (size_t)256 * 128, wt_c2, wt_c2 + (size_t)256 * 256,
        wt_W3, wt_c1 + (size_t)512 * 128, wt_f2, We1, ae1, We2, ae2, We3, ae3, ce_g,
        ei, deg, rank, E);
    scan_block_kernel<<<nb, 256, 0, stream>>>(deg, incl, blocksum, Nn);
    scan_final_kernel<<<nb, 256, 0, stream>>>(deg, incl, blocksum, row_ptr, Nn);
    scatter_kernel<<<eb, 256, 0, stream>>>(ei, ea, row_ptr, rank, csr2, E);

    int mb  = (Nn + 63) / 64;     // 782
    int mb1 = (Nn + 127) / 128;   // 391
    int ab  = (Nn + 3) / 4;       // 12500

    // xg = x * sigmoid(x@fa_w + fa_b)
    gemm_kernel<3, 128><<<dim3(mb, 2), 256, 0, stream>>>(xbf, wt_fa, fa_b, xbf, xg_bf, 128);
    // fused: [xr1 | h1 | mid=relu(xg@fw1+fb1)] = xg @ [r1|W1|fw1]
    gemm128_kernel<6, 128><<<dim3(mb1, 5), 256, 0, stream>>>(xg_bf, wt_c1, r1_b, fb1,
                                                             residB, h_bf, mid_bf);
    att4_kernel<<<ab, 256, 0, stream>>>((const uint2*)h_bf, as1, ad1, att_s, att_d, Nn);
    agg4_kernel<<<ab, 256, 0, stream>>>((const uint2*)h_bf, att_s, att_d, row_ptr, csr2,
                                        ce_g, b1, (const uint2*)residB, z_bf, Nn);
    // fused: [xr2 | h2] = z1 @ [r2|W2]
    gemm128_kernel<4, 256><<<dim3(mb1, 4), 256, 0, stream>>>(z_bf, wt_c2, r2_b, nullptr,
                                                             residB, h_bf, nullptr);
    att4_kernel<<<ab, 256, 0, stream>>>((const uint2*)h_bf, as2, ad2, att_s, att_d, Nn);
    agg4_kernel<<<ab, 256, 0, stream>>>((const uint2*)h_bf, att_s, att_d, row_ptr, csr2,
                                        ce_g + 4, b2, (const uint2*)residB, z_bf, Nn);
    // z_self = mid@fw2 + fb2
    gemm_kernel<1, 64><<<dim3(mb, 1), 256, 0, stream>>>(mid_bf, wt_f2, fb2, nullptr, zself, 64);
    // h3 = z2@W3
    gemm_kernel<0, 256><<<dim3(mb, 1), 256, 0, stream>>>(z_bf, wt_W3, nullptr, nullptr, h3_bf, 64);
    att1_kernel<<<ab, 256, 0, stream>>>((const u32*)h3_bf, as3, ad3, att_s, att_d, Nn);
    agg1_kernel<<<ab, 256, 0, stream>>>((const uint2*)h3_bf, att_s, att_d, row_ptr, csr2,
                                        ce_g, b3, (const uint2*)zself, (float*)d_out, Nn);
}

// Round 11
// 487.258 us; speedup vs baseline: 1.0478x; 1.0154x over previous
//
#include <hip/hip_runtime.h>
#include <hip/hip_bf16.h>

// GATNodeEdgePrediction on MI355X (gfx950) — Round 11.
//  - Edge atomics (rank/deg) fused into the fa-gate GEMM as interleaved grid
//    roles (x%3==2 -> grid-stride atomics). The 800K returning device atomics
//    were a standalone 70 us dispatch at 1% VALU; now they co-schedule with
//    MFMA waves (m114) and their latency hides.
//  - Scatter fused into the c1 GEMM the same way (x%6==5).
//  - prep_mega reduced to conversions only (~12 us).

typedef unsigned short u16;
typedef unsigned int   u32;
typedef __attribute__((ext_vector_type(8))) short short8;
typedef __attribute__((ext_vector_type(4))) float float4v;

typedef const __attribute__((address_space(1))) u32* gptr_t;
typedef __attribute__((address_space(3))) u32* lptr_t;
#define GLOAD_LDS16(g, l) \
    __builtin_amdgcn_global_load_lds((gptr_t)(const void*)(g), (lptr_t)(void*)(l), 16, 0, 0)

static __device__ __forceinline__ u16 f2b(float f) {
    u32 u = __float_as_uint(f);
    u32 r = u + 0x7fffu + ((u >> 16) & 1u);  // RNE
    return (u16)(r >> 16);
}
static __device__ __forceinline__ float b2f(u16 u) {
    return __uint_as_float(((u32)u) << 16);
}
static __device__ __forceinline__ float lo2f(u32 v) { return __uint_as_float(v << 16); }
static __device__ __forceinline__ float hi2f(u32 v) { return __uint_as_float(v & 0xffff0000u); }
static __device__ __forceinline__ float lrelu02(float x) { return fmaxf(x, 0.2f * x); }

// ---------------------------------------------------------------- prep (conversions only)
__global__ void prep_mega(const float* __restrict__ x, u16* __restrict__ xb, int n4,
                          const float* s0, const float* s1, const float* s2,
                          const float* s3, const float* s4, const float* s5,
                          const float* s6, const float* s7,
                          u16* d0, u16* d1, u16* d2, u16* d3,
                          u16* d4, u16* d5, u16* d6, u16* d7,
                          const float* We1, const float* ae1,
                          const float* We2, const float* ae2,
                          const float* We3, const float* ae3, float* ce_g) {
    int role = blockIdx.y;
    if (role == 0) {
        int i = blockIdx.x * 256 + threadIdx.x;
        if (i >= n4) return;
        float4 v = ((const float4*)x)[i];
        ushort4 o;
        o.x = f2b(v.x); o.y = f2b(v.y); o.z = f2b(v.z); o.w = f2b(v.w);
        ((ushort4*)xb)[i] = o;
    } else {
        int wid = blockIdx.x >> 4, sub = blockIdx.x & 15;
        if (wid > 8) return;
        if (wid == 8) {
            if (sub == 0) {
                int t = threadIdx.x;
                if (t < 9) {
                    const float* W; const float* a; int h;
                    if (t < 4)      { W = We1; a = ae1; h = t; }
                    else if (t < 8) { W = We2; a = ae2; h = t - 4; }
                    else            { W = We3; a = ae3; h = 0; }
                    float s = 0.f;
                    for (int c = 0; c < 64; c++) s += W[h * 64 + c] * a[h * 64 + c];
                    ce_g[t] = s;
                }
            }
            return;
        }
        const float* src; u16* dst; int K, N;
        switch (wid) {
            case 0: src = s0; dst = d0; K = 128; N = 128; break;
            case 1: src = s1; dst = d1; K = 128; N = 256; break;
            case 2: src = s2; dst = d2; K = 128; N = 256; break;
            case 3: src = s3; dst = d3; K = 256; N = 256; break;
            case 4: src = s4; dst = d4; K = 256; N = 256; break;
            case 5: src = s5; dst = d5; K = 256; N = 64;  break;
            case 6: src = s6; dst = d6; K = 128; N = 64;  break;
            default: src = s7; dst = d7; K = 64;  N = 64;  break;
        }
        int KN = K * N;
        int nmask = N - 1;
        int nshift = __popc((u32)nmask);
        for (int i = sub * 256 + threadIdx.x; i < KN; i += 16 * 256) {
            int k = i >> nshift, n2 = i & nmask;
            dst[(size_t)n2 * K + k] = f2b(src[i]);
        }
    }
}

// ---------------------------------------------------------------- CSR build
__global__ void scan_block_kernel(const u32* __restrict__ deg, int* incl,
                                  int* blocksum, int Nn) {
    __shared__ int sb[256];
    int t = threadIdx.x;
    int n = blockIdx.x * 256 + t;
    int v = (n < Nn) ? (int)deg[n] : 0;
    sb[t] = v;
    __syncthreads();
    for (int off = 1; off < 256; off <<= 1) {
        int x = (t >= off) ? sb[t - off] : 0;
        __syncthreads();
        sb[t] += x;
        __syncthreads();
    }
    if (n < Nn) incl[n] = sb[t];
    if (t == 255) blocksum[blockIdx.x] = sb[255];
}

__global__ void scan_final_kernel(const u32* __restrict__ deg, const int* __restrict__ incl,
                                  const int* __restrict__ blocksum,
                                  int* row_ptr, int Nn) {
    __shared__ int sb[256];
    int t = threadIdx.x;
    int b = blockIdx.x;
    sb[t] = (t < b) ? blocksum[t] : 0;   // gridDim <= 256
    __syncthreads();
    for (int off = 128; off > 0; off >>= 1) {
        if (t < off) sb[t] += sb[t + off];
        __syncthreads();
    }
    int base = sb[0];
    int n = b * 256 + t;
    if (n >= Nn) return;
    int d = (int)deg[n];
    int excl = base + incl[n] - d;
    row_ptr[n] = excl;
    if (n == Nn - 1) row_ptr[Nn] = excl + d;
}

// ---------------------------------------------------------------- fa gate GEMM + edge atomics
// 1D grid, role = x%3: 0,1 -> 64x64 gemm tile (bn=role); 2 -> edge-atomic chunk.
#define LDSS 40
__global__ __launch_bounds__(256)
void fa_atomic_kernel(const u16* __restrict__ A, const u16* __restrict__ Bt,
                      const float* __restrict__ bias, const u16* __restrict__ extraB,
                      u16* __restrict__ Cb,
                      const int* __restrict__ ei, u32* deg, u32* rank, int E, int nx) {
    int gid = blockIdx.x;
    int role = gid % 3;
    int idx = gid / 3;
    if (role == 2) {
        for (int e = idx * 256 + threadIdx.x; e < E; e += nx * 256)
            rank[e] = atomicAdd(&deg[ei[E + e]], 1u);
        return;
    }
    __shared__ u16 As[64 * LDSS];
    __shared__ u16 Bs[64 * LDSS];
    const int K = 128, N = 128;
    int t = threadIdx.x;
    int bm = idx * 64, bn = role * 64;
    int w = t >> 6, lane = t & 63;
    int wm = w & 1, wn = w >> 1;
    int lm = lane & 15, q = lane >> 4;

    float4v acc[2][2];
#pragma unroll
    for (int i = 0; i < 2; i++)
#pragma unroll
        for (int j = 0; j < 2; j++) acc[i][j] = (float4v){0.f, 0.f, 0.f, 0.f};

    int ar = t >> 2;
    int ac = (t & 3) * 8;
    const u16* aPtr = A + (size_t)(bm + ar) * K + ac;
    const u16* bPtr = Bt + (size_t)(bn + ar) * K + ac;

#pragma unroll
    for (int k0 = 0; k0 < K; k0 += 32) {
        uint4 av = *(const uint4*)(aPtr + k0);
        uint4 bv = *(const uint4*)(bPtr + k0);
        *(uint4*)&As[ar * LDSS + ac] = av;
        *(uint4*)&Bs[ar * LDSS + ac] = bv;
        __syncthreads();

        short8 fa0 = *(const short8*)&As[(32 * wm + lm) * LDSS + q * 8];
        short8 fa1 = *(const short8*)&As[(32 * wm + 16 + lm) * LDSS + q * 8];
        short8 fb0 = *(const short8*)&Bs[(32 * wn + lm) * LDSS + q * 8];
        short8 fb1 = *(const short8*)&Bs[(32 * wn + 16 + lm) * LDSS + q * 8];
        acc[0][0] = __builtin_amdgcn_mfma_f32_16x16x32_bf16(fa0, fb0, acc[0][0], 0, 0, 0);
        acc[0][1] = __builtin_amdgcn_mfma_f32_16x16x32_bf16(fa0, fb1, acc[0][1], 0, 0, 0);
        acc[1][0] = __builtin_amdgcn_mfma_f32_16x16x32_bf16(fa1, fb0, acc[1][0], 0, 0, 0);
        acc[1][1] = __builtin_amdgcn_mfma_f32_16x16x32_bf16(fa1, fb1, acc[1][1], 0, 0, 0);
        __syncthreads();
    }

#pragma unroll
    for (int i = 0; i < 2; i++)
#pragma unroll
        for (int j = 0; j < 2; j++) {
            int col = bn + 32 * wn + 16 * j + lm;
            float bval = bias[col];
#pragma unroll
            for (int r = 0; r < 4; r++) {
                int row = bm + 32 * wm + 16 * i + q * 4 + r;
                float v = acc[i][j][r] + bval;
                float xv = b2f(extraB[(size_t)row * N + col]);
                v = xv / (1.f + __expf(-v));
                Cb[(size_t)row * N + col] = f2b(v);
            }
        }
}

// ---------------------------------------------------------------- c1 GEMM128 + scatter
// 1D grid, role = x%6: 0..4 -> 128x128 gemm tile (bn=128*role, N=640 region
// epilogue: resid+b1 / h / relu+b2->mid); 5 -> scatter chunk.
__global__ __launch_bounds__(256)
void c1_scatter_kernel(const u16* __restrict__ A, const u16* __restrict__ Bt,
                       const float* __restrict__ bias1, const float* __restrict__ bias2,
                       u16* __restrict__ Cres, u16* __restrict__ Ch, u16* __restrict__ Cmid,
                       const int* __restrict__ ei, const float* __restrict__ ea,
                       const int* __restrict__ row_ptr, const u32* __restrict__ rank,
                       int2* __restrict__ csr2, int E, int nx) {
    int gid = blockIdx.x;
    int role = gid % 6;
    int idx = gid / 6;
    if (role == 5) {
        for (int e = idx * 256 + threadIdx.x; e < E; e += nx * 256) {
            int d = ei[E + e];
            csr2[row_ptr[d] + (int)rank[e]] = make_int2(ei[e], __float_as_int(ea[e]));
        }
        return;
    }
    __shared__ u16 As[128 * 32];
    __shared__ u16 Bs[128 * 32];
    const int K = 128;
    int t = threadIdx.x;
    int w = t >> 6, lane = t & 63;
    int wm = w & 1, wn = w >> 1;
    int lm = lane & 15, q = lane >> 4;
    int bm = idx * 128, bn = role * 128;

    float4v acc[4][4];
#pragma unroll
    for (int i = 0; i < 4; i++)
#pragma unroll
        for (int j = 0; j < 4; j++) acc[i][j] = (float4v){0.f, 0.f, 0.f, 0.f};

    int srow = lane >> 2;
    int scol = (lane & 3) * 8;
    const u16* aG = A + (size_t)(bm + w * 32 + srow) * K + scol;
    const u16* bG = Bt + (size_t)(bn + w * 32 + srow) * K + scol;
    u16* aL0 = &As[(w * 32) * 32];
    u16* aL1 = &As[(w * 32 + 16) * 32];
    u16* bL0 = &Bs[(w * 32) * 32];
    u16* bL1 = &Bs[(w * 32 + 16) * 32];

#pragma unroll
    for (int k0 = 0; k0 < K; k0 += 32) {
        GLOAD_LDS16(aG + k0, aL0);
        GLOAD_LDS16(aG + (size_t)16 * K + k0, aL1);
        GLOAD_LDS16(bG + k0, bL0);
        GLOAD_LDS16(bG + (size_t)16 * K + k0, bL1);
        __syncthreads();

        short8 af[4], bf[4];
#pragma unroll
        for (int i = 0; i < 4; i++)
            af[i] = *(const short8*)&As[(64 * wm + 16 * i + lm) * 32 + q * 8];
#pragma unroll
        for (int j = 0; j < 4; j++)
            bf[j] = *(const short8*)&Bs[(64 * wn + 16 * j + lm) * 32 + q * 8];
#pragma unroll
        for (int i = 0; i < 4; i++)
#pragma unroll
            for (int j = 0; j < 4; j++)
                acc[i][j] = __builtin_amdgcn_mfma_f32_16x16x32_bf16(af[i], bf[j], acc[i][j], 0, 0, 0);
        __syncthreads();
    }

#pragma unroll
    for (int i = 0; i < 4; i++)
#pragma unroll
        for (int j = 0; j < 4; j++) {
            int col = bn + 64 * wn + 16 * j + lm;
#pragma unroll
            for (int r = 0; r < 4; r++) {
                int row = bm + 64 * wm + 16 * i + q * 4 + r;
                float v = acc[i][j][r];
                if (col < 256) {
                    Cres[(size_t)row * 256 + col] = f2b(v + bias1[col]);
                } else if (col < 512) {
                    Ch[(size_t)row * 256 + (col - 256)] = f2b(v);
                } else if (col < 576) {
                    Cmid[(size_t)row * 64 + (col - 512)] = f2b(fmaxf(v + bias2[col - 512], 0.f));
                }
            }
        }
}

// ---------------------------------------------------------------- GEMM 128x128 (c2)
// EPI 4 (N=512): col<256 -> bf16 resid (+bias1); col>=256 -> bf16 h.
template <int K>
__global__ __launch_bounds__(256)
void gemm128_kernel(const u16* __restrict__ A, const u16* __restrict__ Bt,
                    const float* __restrict__ bias1,
                    u16* __restrict__ Cres, u16* __restrict__ Ch) {
    __shared__ u16 As[128 * 32];
    __shared__ u16 Bs[128 * 32];
    int t = threadIdx.x;
    int w = t >> 6, lane = t & 63;
    int wm = w & 1, wn = w >> 1;
    int lm = lane & 15, q = lane >> 4;
    int bm = blockIdx.x * 128, bn = blockIdx.y * 128;

    float4v acc[4][4];
#pragma unroll
    for (int i = 0; i < 4; i++)
#pragma unroll
        for (int j = 0; j < 4; j++) acc[i][j] = (float4v){0.f, 0.f, 0.f, 0.f};

    int srow = lane >> 2;
    int scol = (lane & 3) * 8;
    const u16* aG = A + (size_t)(bm + w * 32 + srow) * K + scol;
    const u16* bG = Bt + (size_t)(bn + w * 32 + srow) * K + scol;
    u16* aL0 = &As[(w * 32) * 32];
    u16* aL1 = &As[(w * 32 + 16) * 32];
    u16* bL0 = &Bs[(w * 32) * 32];
    u16* bL1 = &Bs[(w * 32 + 16) * 32];

#pragma unroll
    for (int k0 = 0; k0 < K; k0 += 32) {
        GLOAD_LDS16(aG + k0, aL0);
        GLOAD_LDS16(aG + (size_t)16 * K + k0, aL1);
        GLOAD_LDS16(bG + k0, bL0);
        GLOAD_LDS16(bG + (size_t)16 * K + k0, bL1);
        __syncthreads();

        short8 af[4], bf[4];
#pragma unroll
        for (int i = 0; i < 4; i++)
            af[i] = *(const short8*)&As[(64 * wm + 16 * i + lm) * 32 + q * 8];
#pragma unroll
        for (int j = 0; j < 4; j++)
            bf[j] = *(const short8*)&Bs[(64 * wn + 16 * j + lm) * 32 + q * 8];
#pragma unroll
        for (int i = 0; i < 4; i++)
#pragma unroll
            for (int j = 0; j < 4; j++)
                acc[i][j] = __builtin_amdgcn_mfma_f32_16x16x32_bf16(af[i], bf[j], acc[i][j], 0, 0, 0);
        __syncthreads();
    }

#pragma unroll
    for (int i = 0; i < 4; i++)
#pragma unroll
        for (int j = 0; j < 4; j++) {
            int col = bn + 64 * wn + 16 * j + lm;
#pragma unroll
            for (int r = 0; r < 4; r++) {
                int row = bm + 64 * wm + 16 * i + q * 4 + r;
                float v = acc[i][j][r];
                if (col < 256) {
                    Cres[(size_t)row * 256 + col] = f2b(v + bias1[col]);
                } else {
                    Ch[(size_t)row * 256 + (col - 256)] = f2b(v);
                }
            }
        }
}

// ---------------------------------------------------------------- GEMM 64x64
// EPI: 0 plain->bf16, 1 +bias->bf16.
template <int EPI, int K>
__global__ __launch_bounds__(256)
void gemm_kernel(const u16* __restrict__ A, const u16* __restrict__ Bt,
                 const float* __restrict__ bias, u16* __restrict__ Cb, int N) {
    __shared__ u16 As[64 * LDSS];
    __shared__ u16 Bs[64 * LDSS];
    int t = threadIdx.x;
    int bm = blockIdx.x * 64, bn = blockIdx.y * 64;
    int w = t >> 6, lane = t & 63;
    int wm = w & 1, wn = w >> 1;
    int lm = lane & 15, q = lane >> 4;

    float4v acc[2][2];
#pragma unroll
    for (int i = 0; i < 2; i++)
#pragma unroll
        for (int j = 0; j < 2; j++) acc[i][j] = (float4v){0.f, 0.f, 0.f, 0.f};

    int ar = t >> 2;
    int ac = (t & 3) * 8;
    const u16* aPtr = A + (size_t)(bm + ar) * K + ac;
    const u16* bPtr = Bt + (size_t)(bn + ar) * K + ac;

#pragma unroll
    for (int k0 = 0; k0 < K; k0 += 32) {
        uint4 av = *(const uint4*)(aPtr + k0);
        uint4 bv = *(const uint4*)(bPtr + k0);
        *(uint4*)&As[ar * LDSS + ac] = av;
        *(uint4*)&Bs[ar * LDSS + ac] = bv;
        __syncthreads();

        short8 fa0 = *(const short8*)&As[(32 * wm + lm) * LDSS + q * 8];
        short8 fa1 = *(const short8*)&As[(32 * wm + 16 + lm) * LDSS + q * 8];
        short8 fb0 = *(const short8*)&Bs[(32 * wn + lm) * LDSS + q * 8];
        short8 fb1 = *(const short8*)&Bs[(32 * wn + 16 + lm) * LDSS + q * 8];
        acc[0][0] = __builtin_amdgcn_mfma_f32_16x16x32_bf16(fa0, fb0, acc[0][0], 0, 0, 0);
        acc[0][1] = __builtin_amdgcn_mfma_f32_16x16x32_bf16(fa0, fb1, acc[0][1], 0, 0, 0);
        acc[1][0] = __builtin_amdgcn_mfma_f32_16x16x32_bf16(fa1, fb0, acc[1][0], 0, 0, 0);
        acc[1][1] = __builtin_amdgcn_mfma_f32_16x16x32_bf16(fa1, fb1, acc[1][1], 0, 0, 0);
        __syncthreads();
    }

#pragma unroll
    for (int i = 0; i < 2; i++)
#pragma unroll
        for (int j = 0; j < 2; j++) {
            int col = bn + 32 * wn + 16 * j + lm;
            float bval = (EPI >= 1) ? bias[col] : 0.f;
#pragma unroll
            for (int r = 0; r < 4; r++) {
                int row = bm + 32 * wm + 16 * i + q * 4 + r;
                float v = acc[i][j][r] + bval;
                Cb[(size_t)row * N + col] = f2b(v);
            }
        }
}

// ---------------------------------------------------------------- attention dots
__global__ __launch_bounds__(256)
void att4_kernel(const uint2* __restrict__ hb2, const float* __restrict__ a_s,
                 const float* __restrict__ a_d, float* att_s, float* att_d, int Nn) {
    int wv = threadIdx.x >> 6;
    int n = blockIdx.x * 4 + wv;
    if (n >= Nn) return;
    int lane = threadIdx.x & 63;
    float4 as4 = *(const float4*)&a_s[lane * 4];
    float4 ad4 = *(const float4*)&a_d[lane * 4];
    uint2 v = hb2[(size_t)n * 64 + lane];
    float c0 = lo2f(v.x), c1 = hi2f(v.x), c2 = lo2f(v.y), c3 = hi2f(v.y);
    float ps = c0 * as4.x + c1 * as4.y + c2 * as4.z + c3 * as4.w;
    float pd = c0 * ad4.x + c1 * ad4.y + c2 * ad4.z + c3 * ad4.w;
#pragma unroll
    for (int off = 8; off > 0; off >>= 1) {
        ps += __shfl_down(ps, off);
        pd += __shfl_down(pd, off);
    }
    if ((lane & 15) == 0) {
        att_s[n * 4 + (lane >> 4)] = ps;
        att_d[n * 4 + (lane >> 4)] = pd;
    }
}

__global__ __launch_bounds__(256)
void att1_kernel(const u32* __restrict__ hb, const float* __restrict__ a_s,
                 const float* __restrict__ a_d, float* att_s, float* att_d, int Nn) {
    int wv = threadIdx.x >> 6;
    int n = blockIdx.x * 4 + wv;
    if (n >= Nn) return;
    int lane = threadIdx.x & 63;
    int cl = lane & 31;
    float2 as2 = *(const float2*)&a_s[cl * 2];
    float2 ad2 = *(const float2*)&a_d[cl * 2];
    u32 v = hb[(u32)n * 32u + cl];
    float c0 = lo2f(v), c1 = hi2f(v);
    float ps = c0 * as2.x + c1 * as2.y;
    float pd = c0 * ad2.x + c1 * ad2.y;
    if (lane >= 32) { ps = 0.f; pd = 0.f; }
#pragma unroll
    for (int off = 16; off > 0; off >>= 1) {
        ps += __shfl_down(ps, off);
        pd += __shfl_down(pd, off);
    }
    if (lane == 0) {
        att_s[n] = ps;
        att_d[n] = pd;
    }
}

// ---------------------------------------------------------------- GAT aggregate H=4
__global__ __launch_bounds__(256)
void agg4_kernel(const uint2* __restrict__ hb2,  // [Nn][64] uint2 (256 bf16 ch)
                 const float* __restrict__ att_s, const float* __restrict__ att_d,
                 const int* __restrict__ row_ptr, const int2* __restrict__ csr2,
                 const float* __restrict__ ce_g, const float* __restrict__ bias,
                 const uint2* __restrict__ resid2, u16* __restrict__ outb, int Nn) {
    int wv = __builtin_amdgcn_readfirstlane(threadIdx.x >> 6);
    int n = blockIdx.x * 4 + wv;
    if (n >= Nn) return;
    int lane = threadIdx.x & 63;
    int hh = lane >> 4;

    float ce = ce_g[hh];
    float adn = att_d[n * 4 + hh];
    float asn = att_s[n * 4 + hh];
    uint2 sv = hb2[(size_t)n * 64 + lane];
    float z = 0.f, qsum = 0.f;
    float aA0 = 0.f, aA1 = 0.f, aA2 = 0.f, aA3 = 0.f;
    float aB0 = 0.f, aB1 = 0.f, aB2 = 0.f, aB3 = 0.f;

    int e0 = row_ptr[n], e1 = row_ptr[n + 1];
    for (int base = e0; base < e1; base += 64) {
        int cnt = min(64, e1 - base);
        int2 cc = csr2[base + min(lane, cnt - 1)];
        int vsrc = cc.x;
        float vea = __int_as_float(cc.y);
        int i = 0;
        for (; i + 4 <= cnt; i += 4) {
            int sA = __shfl(vsrc, i),     sB = __shfl(vsrc, i + 1);
            int sC = __shfl(vsrc, i + 2), sD = __shfl(vsrc, i + 3);
            float qA = __shfl(vea, i),     qB = __shfl(vea, i + 1);
            float qC = __shfl(vea, i + 2), qD = __shfl(vea, i + 3);
            float gA = att_s[(u32)sA * 4u + hh], gB = att_s[(u32)sB * 4u + hh];
            float gC = att_s[(u32)sC * 4u + hh], gD = att_s[(u32)sD * 4u + hh];
            uint2 vA = hb2[(u32)sA * 64u + lane], vB = hb2[(u32)sB * 64u + lane];
            uint2 vC = hb2[(u32)sC * 64u + lane], vD = hb2[(u32)sD * 64u + lane];
            float pA = __expf(lrelu02(gA + adn + qA * ce));
            float pB = __expf(lrelu02(gB + adn + qB * ce));
            float pC = __expf(lrelu02(gC + adn + qC * ce));
            float pD = __expf(lrelu02(gD + adn + qD * ce));
            qsum += (qA + qB) + (qC + qD);
            z += (pA + pB) + (pC + pD);
            aA0 = fmaf(pA, lo2f(vA.x), aA0); aA1 = fmaf(pA, hi2f(vA.x), aA1);
            aA2 = fmaf(pA, lo2f(vA.y), aA2); aA3 = fmaf(pA, hi2f(vA.y), aA3);
            aB0 = fmaf(pB, lo2f(vB.x), aB0); aB1 = fmaf(pB, hi2f(vB.x), aB1);
            aB2 = fmaf(pB, lo2f(vB.y), aB2); aB3 = fmaf(pB, hi2f(vB.y), aB3);
            aA0 = fmaf(pC, lo2f(vC.x), aA0); aA1 = fmaf(pC, hi2f(vC.x), aA1);
            aA2 = fmaf(pC, lo2f(vC.y), aA2); aA3 = fmaf(pC, hi2f(vC.y), aA3);
            aB0 = fmaf(pD, lo2f(vD.x), aB0); aB1 = fmaf(pD, hi2f(vD.x), aB1);
            aB2 = fmaf(pD, lo2f(vD.y), aB2); aB3 = fmaf(pD, hi2f(vD.y), aB3);
        }
        for (; i < cnt; i++) {
            int s = __shfl(vsrc, i);
            float q = __shfl(vea, i);
            float g = att_s[(u32)s * 4u + hh];
            uint2 v = hb2[(u32)s * 64u + lane];
            float p = __expf(lrelu02(g + adn + q * ce));
            qsum += q;
            z += p;
            aA0 = fmaf(p, lo2f(v.x), aA0); aA1 = fmaf(p, hi2f(v.x), aA1);
            aA2 = fmaf(p, lo2f(v.y), aA2); aA3 = fmaf(p, hi2f(v.y), aA3);
        }
    }
    float la = qsum / (float)max(e1 - e0, 1);
    float ps = __expf(lrelu02(asn + adn + la * ce));
    z += ps;
    float a0 = aA0 + aB0 + ps * lo2f(sv.x);
    float a1 = aA1 + aB1 + ps * hi2f(sv.x);
    float a2 = aA2 + aB2 + ps * lo2f(sv.y);
    float a3 = aA3 + aB3 + ps * hi2f(sv.y);

    float inv = 1.f / z;
    int c0 = lane * 4;
    float4 bv = *(const float4*)&bias[c0];
    uint2 rr = resid2[(size_t)n * 64 + lane];
    float o0 = fmaf(a0, inv, bv.x);
    float o1 = fmaf(a1, inv, bv.y);
    float o2 = fmaf(a2, inv, bv.z);
    float o3 = fmaf(a3, inv, bv.w);
    o0 = fmaxf(o0, 0.01f * o0) + lo2f(rr.x);
    o1 = fmaxf(o1, 0.01f * o1) + hi2f(rr.x);
    o2 = fmaxf(o2, 0.01f * o2) + lo2f(rr.y);
    o3 = fmaxf(o3, 0.01f * o3) + hi2f(rr.y);
    uint2 packed;
    packed.x = ((u32)f2b(o0)) | (((u32)f2b(o1)) << 16);
    packed.y = ((u32)f2b(o2)) | (((u32)f2b(o3)) << 16);
    ((uint2*)outb)[(size_t)n * 64 + lane] = packed;
}

// ---------------------------------------------------------------- GAT aggregate H=1
__global__ __launch_bounds__(256)
void agg1_kernel(const uint2* __restrict__ hb2,  // [Nn][16] uint2 (64 bf16 ch)
                 const float* __restrict__ att_s, const float* __restrict__ att_d,
                 const int* __restrict__ row_ptr, const int2* __restrict__ csr2,
                 const float* __restrict__ ce_g, const float* __restrict__ bias,
                 const uint2* __restrict__ zs2, float* __restrict__ outf, int Nn) {
    int wv = __builtin_amdgcn_readfirstlane(threadIdx.x >> 6);
    int n = blockIdx.x * 4 + wv;
    if (n >= Nn) return;
    int lane = threadIdx.x & 63;
    int qtr = lane >> 4;
    int cl = lane & 15;

    float ce = ce_g[8];
    float adn = att_d[n];
    float asn = att_s[n];
    uint2 sv = hb2[(u32)n * 16u + cl];
    float z = 0.f, qsum = 0.f;
    float a0 = 0.f, a1 = 0.f, a2 = 0.f, a3 = 0.f;

    int e0 = row_ptr[n], e1 = row_ptr[n + 1];
    for (int base = e0; base < e1; base += 64) {
        int cnt = min(64, e1 - base);
        int2 cc = csr2[base + min(lane, cnt - 1)];
        int vsrc = cc.x;
        float vea = __int_as_float(cc.y);
        for (int i = 0; i < cnt; i += 4) {
            int idx = min(i + qtr, cnt - 1);
            int s = __shfl(vsrc, idx);
            float q = __shfl(vea, idx);
            bool act = (i + qtr < cnt);
            float p = __expf(lrelu02(att_s[s] + adn + q * ce));
            p = act ? p : 0.f;
            q = act ? q : 0.f;
            uint2 v = hb2[(u32)s * 16u + cl];
            z += p;
            qsum += q;
            a0 = fmaf(p, lo2f(v.x), a0);
            a1 = fmaf(p, hi2f(v.x), a1);
            a2 = fmaf(p, lo2f(v.y), a2);
            a3 = fmaf(p, hi2f(v.y), a3);
        }
    }
    z += __shfl_xor(z, 16);       z += __shfl_xor(z, 32);
    qsum += __shfl_xor(qsum, 16); qsum += __shfl_xor(qsum, 32);
    a0 += __shfl_xor(a0, 16);     a0 += __shfl_xor(a0, 32);
    a1 += __shfl_xor(a1, 16);     a1 += __shfl_xor(a1, 32);
    a2 += __shfl_xor(a2, 16);     a2 += __shfl_xor(a2, 32);
    a3 += __shfl_xor(a3, 16);     a3 += __shfl_xor(a3, 32);

    float la = qsum / (float)max(e1 - e0, 1);
    float ps = __expf(lrelu02(asn + adn + la * ce));
    z += ps;
    a0 += ps * lo2f(sv.x);
    a1 += ps * hi2f(sv.x);
    a2 += ps * lo2f(sv.y);
    a3 += ps * hi2f(sv.y);

    if (lane < 16) {
        float inv = 1.f / z;
        int c0 = cl * 4;
        float4 bv = *(const float4*)&bias[c0];
        uint2 zz = zs2[(u32)n * 16u + cl];
        float o0 = fmaf(a0, inv, bv.x);
        float o1 = fmaf(a1, inv, bv.y);
        float o2 = fmaf(a2, inv, bv.z);
        float o3 = fmaf(a3, inv, bv.w);
        o0 = fmaxf(o0, 0.01f * o0) + lo2f(zz.x);
        o1 = fmaxf(o1, 0.01f * o1) + hi2f(zz.x);
        o2 = fmaxf(o2, 0.01f * o2) + lo2f(zz.y);
        o3 = fmaxf(o3, 0.01f * o3) + hi2f(zz.y);
        *(float4*)&outf[(size_t)n * 64 + c0] = make_float4(o0, o1, o2, o3);
    }
}

// ---------------------------------------------------------------- launch
extern "C" void kernel_launch(void* const* d_in, const int* in_sizes, int n_in,
                              void* d_out, int out_size, void* d_ws, size_t ws_size,
                              hipStream_t stream) {
    const float* x    = (const float*)d_in[0];
    const int*   ei   = (const int*)d_in[1];
    const float* ea   = (const float*)d_in[2];
    const float* fa_w = (const float*)d_in[3];
    const float* fa_b = (const float*)d_in[4];
    const float* W1   = (const float*)d_in[5];
    const float* We1  = (const float*)d_in[6];
    const float* as1  = (const float*)d_in[7];
    const float* ad1  = (const float*)d_in[8];
    const float* ae1  = (const float*)d_in[9];
    const float* b1   = (const float*)d_in[10];
    const float* W2   = (const float*)d_in[11];
    const float* We2  = (const float*)d_in[12];
    const float* as2  = (const float*)d_in[13];
    const float* ad2  = (const float*)d_in[14];
    const float* ae2  = (const float*)d_in[15];
    const float* b2   = (const float*)d_in[16];
    const float* W3   = (const float*)d_in[17];
    const float* We3  = (const float*)d_in[18];
    const float* as3  = (const float*)d_in[19];
    const float* ad3  = (const float*)d_in[20];
    const float* ae3  = (const float*)d_in[21];
    const float* b3   = (const float*)d_in[22];
    const float* r1_w = (const float*)d_in[23];
    const float* r1_b = (const float*)d_in[24];
    const float* r2_w = (const float*)d_in[25];
    const float* r2_b = (const float*)d_in[26];
    const float* fw1  = (const float*)d_in[27];
    const float* fb1  = (const float*)d_in[28];
    const float* fw2  = (const float*)d_in[29];
    const float* fb2  = (const float*)d_in[30];

    const int Nn = in_sizes[0] / 128;
    const int E  = in_sizes[1] / 2;

    char* ws = (char*)d_ws;
    size_t off = 0;
    auto alloc = [&](size_t bytes) -> char* {
        char* p = ws + off;
        off += (bytes + 255) & ~((size_t)255);
        return p;
    };
    u32*   deg      = (u32*)alloc((size_t)Nn * 4);       // memset target
    u32*   rank     = (u32*)alloc((size_t)E * 4);
    int*   incl     = (int*)alloc((size_t)Nn * 4);
    int*   row_ptr  = (int*)alloc((size_t)(Nn + 1) * 4);
    int*   blocksum = (int*)alloc(1024);
    float* att_s    = (float*)alloc((size_t)Nn * 16);
    float* att_d    = (float*)alloc((size_t)Nn * 16);
    int2*  csr2     = (int2*)alloc((size_t)E * 8);
    float* ce_g     = (float*)alloc(64);
    u16* xbf   = (u16*)alloc((size_t)(Nn + 128) * 128 * 2);
    u16* xg_bf = (u16*)alloc((size_t)(Nn + 128) * 128 * 2);
    u16* h_bf  = (u16*)alloc((size_t)(Nn + 128) * 256 * 2);
    u16* z_bf  = (u16*)alloc((size_t)(Nn + 128) * 256 * 2);
    u16* mid_bf = (u16*)alloc((size_t)(Nn + 128) * 64 * 2);
    u16* h3_bf  = (u16*)alloc((size_t)(Nn + 128) * 64 * 2);
    u16* wt_fa = (u16*)alloc(16384 * 2);
    u16* wt_c1 = (u16*)alloc((size_t)640 * 128 * 2);   // [r1 | W1 | fw1]
    u16* wt_c2 = (u16*)alloc((size_t)512 * 256 * 2);   // [r2 | W2]
    u16* wt_W3 = (u16*)alloc(16384 * 2);
    u16* wt_f2 = (u16*)alloc(4096 * 2);
    u16* residB = (u16*)alloc((size_t)(Nn + 128) * 256 * 2);  // bf16 residuals
    u16* zself  = (u16*)alloc((size_t)(Nn + 128) * 64 * 2);   // bf16 z_self

    hipMemsetAsync(deg, 0, (size_t)Nn * 4, stream);

    int nb = (Nn + 255) / 256;      // 196 (<= 256 for scan_final)
    int n4 = Nn * 128 / 4;
    int xb4 = (n4 + 255) / 256;     // 6250

    prep_mega<<<dim3(xb4, 2), 256, 0, stream>>>(
        x, xbf, n4,
        fa_w, r1_w, W1, r2_w, W2, W3, fw1, fw2,
        wt_fa, wt_c1, wt_c1 + (size_t)256 * 128, wt_c2, wt_c2 + (size_t)256 * 256,
        wt_W3, wt_c1 + (size_t)512 * 128, wt_f2, We1, ae1, We2, ae2, We3, ae3, ce_g);

    int mb  = (Nn + 63) / 64;     // 782
    int mb1 = (Nn + 127) / 128;   // 391
    int ab  = (Nn + 3) / 4;       // 12500

    // xg = x * sigmoid(x@fa_w + fa_b)  ++  fused edge rank/deg atomics
    fa_atomic_kernel<<<mb * 3, 256, 0, stream>>>(xbf, wt_fa, fa_b, xbf, xg_bf,
                                                 ei, deg, rank, E, mb);
    scan_block_kernel<<<nb, 256, 0, stream>>>(deg, incl, blocksum, Nn);
    scan_final_kernel<<<nb, 256, 0, stream>>>(deg, incl, blocksum, row_ptr, Nn);
    // fused: [xr1 | h1 | mid] = xg @ [r1|W1|fw1]  ++  fused CSR scatter
    c1_scatter_kernel<<<mb1 * 6, 256, 0, stream>>>(xg_bf, wt_c1, r1_b, fb1,
                                                   residB, h_bf, mid_bf,
                                                   ei, ea, row_ptr, rank, csr2, E, mb1);
    att4_kernel<<<ab, 256, 0, stream>>>((const uint2*)h_bf, as1, ad1, att_s, att_d, Nn);
    agg4_kernel<<<ab, 256, 0, stream>>>((const uint2*)h_bf, att_s, att_d, row_ptr, csr2,
                                        ce_g, b1, (const uint2*)residB, z_bf, Nn);
    // fused: [xr2 | h2] = z1 @ [r2|W2]
    gemm128_kernel<256><<<dim3(mb1, 4), 256, 0, stream>>>(z_bf, wt_c2, r2_b, residB, h_bf);
    att4_kernel<<<ab, 256, 0, stream>>>((const uint2*)h_bf, as2, ad2, att_s, att_d, Nn);
    agg4_kernel<<<ab, 256, 0, stream>>>((const uint2*)h_bf, att_s, att_d, row_ptr, csr2,
                                        ce_g + 4, b2, (const uint2*)residB, z_bf, Nn);
    // z_self = mid@fw2 + fb2
    gemm_kernel<1, 64><<<dim3(mb, 1), 256, 0, stream>>>(mid_bf, wt_f2, fb2, zself, 64);
    // h3 = z2@W3
    gemm_kernel<0, 256><<<dim3(mb, 1), 256, 0, stream>>>(z_bf, wt_W3, nullptr, h3_bf, 64);
    att1_kernel<<<ab, 256, 0, stream>>>((const u32*)h3_bf, as3, ad3, att_s, att_d, Nn);
    agg1_kernel<<<ab, 256, 0, stream>>>((const uint2*)h3_bf, att_s, att_d, row_ptr, csr2,
                                        ce_g, b3, (const uint2*)zself, (float*)d_out, Nn);
}